// Round 11
// baseline (411.302 us; speedup 1.0000x reference)
//
#include <hip/hip_runtime.h>
#include <hip/hip_fp16.h>

// GCN: h0 = relu(c_dst ⊙ Agg(c_src ⊙ x @ W0) + b0); h1 = same with W1; out = h1 @ Wc + bc
// R18: kill the src-side bucket chain. c_src now comes from k_degsrc — an 8-copy global-atomic
//      histogram (copy = blockIdx&7, XCD-local L2 if round-robin mapping holds; 8x less
//      contention regardless) + reduce blocks appended to k_partition. Removes sbuf's 1-B/edge
//      scatter (~6 B per (block,bucket) sub-range -> cross-XCD line ping-pong), cntT2/offsT2,
//      k_finalize_src, and k_scantot (absorbed into k_scanblk via last-block + threadfence).
//      Aggregate (65.5 µs / 3.2 TB/s floor), fin_gemm overlap, gemm2, classifier = R17 (344.6).

#define PB 256          // partition blocks
#define BSHIFT 8        // bucket = node >> 8 (256 nodes/bucket)

typedef _Float16 f16x8 __attribute__((ext_vector_type(8)));
typedef float f32x4 __attribute__((ext_vector_type(4)));

// ---------------- src out-degree: 8-copy histogram (1.6M atomics spread over 8 L2-resident copies) ----------------

__global__ __launch_bounds__(256) void k_degsrc(const int* __restrict__ src, int E, int per_blk, int N,
                                                int* __restrict__ deg8) {
  int e0 = blockIdx.x * per_blk, e1 = min(E, e0 + per_blk);
  int* my = deg8 + (size_t)(blockIdx.x & 7) * N;
  for (int e = e0 + threadIdx.x; e < e1; e += 256) atomicAdd(&my[src[e]], 1);
}

// ---------------- Phase A: dst bucket counts ----------------

__global__ __launch_bounds__(256) void k_count(const int* __restrict__ dst, int E, int per_blk, int NB,
                                               int* __restrict__ cntT) {
  __shared__ int cnt[512];
  for (int i = threadIdx.x; i < 512; i += 256) cnt[i] = 0;
  __syncthreads();
  int e0 = blockIdx.x * per_blk, e1 = min(E, e0 + per_blk);
  for (int e = e0 + threadIdx.x; e < e1; e += 256) atomicAdd(&cnt[dst[e] >> BSHIFT], 1);
  __syncthreads();
  for (int i = threadIdx.x; i < NB; i += 256) cntT[i * PB + blockIdx.x] = cnt[i];
}

// per-bucket exclusive scan of the 256 per-block counts; LAST block also scans bucket totals -> bbase
__global__ __launch_bounds__(256) void k_scanblk(const int* __restrict__ cntT, int* __restrict__ offsT,
                                                 int* __restrict__ total, int NB, int E,
                                                 int* __restrict__ bbase, int* __restrict__ row_ptr, int N,
                                                 int* __restrict__ done) {
  __shared__ int s[256];
  __shared__ int amLast;
  int b = blockIdx.x, t = threadIdx.x;
  int v = cntT[b * PB + t];
  s[t] = v;
  __syncthreads();
  for (int off = 1; off < 256; off <<= 1) {
    int x = (t >= off) ? s[t - off] : 0;
    __syncthreads();
    s[t] += x;
    __syncthreads();
  }
  offsT[b * PB + t] = s[t] - v;
  if (t == 255) total[b] = s[255];
  __threadfence();
  if (t == 0) amLast = (atomicAdd(done, 1) == (int)gridDim.x - 1);
  __syncthreads();
  if (!amLast) return;
  __threadfence();
  // scan total[0..NB) -> bbase (chunks of 256 with carry)
  int carry = 0;
  for (int base0 = 0; base0 < NB; base0 += 256) {
    int idx = base0 + t;
    int tv = (idx < NB) ? total[idx] : 0;
    s[t] = tv;
    __syncthreads();
    for (int off = 1; off < 256; off <<= 1) {
      int x = (t >= off) ? s[t - off] : 0;
      __syncthreads();
      s[t] += x;
      __syncthreads();
    }
    if (idx < NB) bbase[idx] = carry + s[t] - tv;
    carry += s[255];
    __syncthreads();
  }
  if (t == 0) {
    bbase[NB] = E;
    row_ptr[N] = E;
  }
}

// ---------------- Phase A: partition scatter (dst-sorted ebuf) + c_src reduce blocks ----------------

__global__ __launch_bounds__(256) void k_partition(const int* __restrict__ src, const int* __restrict__ dst,
                                                   int E, int per_blk, int NB,
                                                   const int* __restrict__ offsT, const int* __restrict__ bbase,
                                                   unsigned* __restrict__ ebuf, int src_bits,
                                                   const int* __restrict__ deg8, float* __restrict__ c_src, int N) {
  if (blockIdx.x >= PB) {
    // ---- c_src reduce: sum the 8 histogram copies ----
    int rb = blockIdx.x - PB;
    int nend = min(N, rb * 1024 + 1024);
    for (int n = rb * 1024 + threadIdx.x; n < nend; n += 256) {
      int s8 = 0;
#pragma unroll
      for (int p = 0; p < 8; p++) s8 += deg8[(size_t)p * N + n];
      c_src[n] = rsqrtf((float)max(s8, 1));
    }
    return;
  }
  __shared__ int cur[512];
  for (int i = threadIdx.x; i < NB; i += 256)
    cur[i] = bbase[i] + offsT[i * PB + blockIdx.x];
  __syncthreads();
  int e0 = blockIdx.x * per_blk, e1 = min(E, e0 + per_blk);
  for (int e = e0 + threadIdx.x; e < e1; e += 256) {
    int d = dst[e], s = src[e];
    int pos = atomicAdd(&cur[d >> BSHIFT], 1);
    ebuf[pos] = ((unsigned)(d & ((1 << BSHIFT) - 1)) << src_bits) | (unsigned)s;
  }
}

// ---------------- fused: blocks [0,NB) = finalize_dst; blocks [NB,..) = gemm1 (x fp32) ----------------

__global__ __launch_bounds__(256) void k_fin_gemm(const unsigned* __restrict__ ebuf, const int* __restrict__ bbase,
                                                  int N, int src_bits, int NB,
                                                  int* __restrict__ row_ptr, float* __restrict__ c_dst,
                                                  int* __restrict__ col_idx,
                                                  const float* __restrict__ A, const float* __restrict__ W,
                                                  const float* __restrict__ scale, __half* __restrict__ out) {
  __shared__ _Float16 Wt[128][136];   // 34.8 KB; finalize path aliases the first 3 KB
  int t = threadIdx.x;

  if (blockIdx.x < NB) {
    int* cnt = (int*)&Wt[0][0];
    int* s = cnt + 256;
    int* cur = cnt + 512;
    int b = blockIdx.x;
    int r0 = bbase[b], r1 = bbase[b + 1];
    cnt[t] = 0;
    __syncthreads();
    for (int i = r0 + t; i < r1; i += 256) atomicAdd(&cnt[ebuf[i] >> src_bits], 1);
    __syncthreads();
    int v = cnt[t];
    s[t] = v;
    __syncthreads();
    for (int off = 1; off < 256; off <<= 1) {
      int x = (t >= off) ? s[t - off] : 0;
      __syncthreads();
      s[t] += x;
      __syncthreads();
    }
    int ex = s[t] - v;
    cur[t] = ex;
    int node = (b << BSHIFT) + t;
    if (node < N) {
      row_ptr[node] = r0 + ex;
      c_dst[node] = rsqrtf((float)max(v, 1));
    }
    __syncthreads();
    unsigned smask = (1u << src_bits) - 1u;
    for (int i = r0 + t; i < r1; i += 256) {
      unsigned e = ebuf[i];
      int pos = r0 + atomicAdd(&cur[e >> src_bits], 1);
      col_idx[pos] = (int)((e & smask) << 8);   // byte offset into fp16 h rows (256 B/row)
    }
    return;
  }

  // ---- gemm1 (R13 LDS form) ----
  int bid = blockIdx.x - NB;
  {
    int nlow = t & 15;
    int kplow = t >> 4;
#pragma unroll
    for (int j = 0; j < 32; j++) {
      int n = nlow + 16 * (j & 7);
      int kp = kplow + 16 * (j >> 3);
      float w0 = W[(size_t)(2 * kp) * 128 + n];
      float w1 = W[(size_t)(2 * kp + 1) * 128 + n];
      __half2 h2 = __floats2half2_rn(w0, w1);
      *(__half2*)&Wt[n][2 * kp] = h2;
    }
  }
  __syncthreads();

  int wave = t >> 6;
  int lane = t & 63;
  int li = lane & 15;
  int q = lane >> 4;

#pragma unroll
  for (int s2 = 0; s2 < 2; s2++) {
    int m0 = (bid * 2 + s2) * 128 + wave * 32;
    if (m0 >= N) break;

    int mrow[2];
    float csc[2];
    bool mok[2];
    const float* arow[2];
#pragma unroll
    for (int s = 0; s < 2; s++) {
      mrow[s] = m0 + s * 16 + li;
      mok[s] = mrow[s] < N;
      csc[s] = mok[s] ? scale[mrow[s]] : 0.f;
      arow[s] = A + (size_t)(mok[s] ? mrow[s] : 0) * 128;
    }

    f32x4 acc[2][8];
#pragma unroll
    for (int s = 0; s < 2; s++)
#pragma unroll
      for (int nt = 0; nt < 8; nt++) acc[s][nt] = (f32x4){0.f, 0.f, 0.f, 0.f};

#pragma unroll
    for (int kc = 0; kc < 128; kc += 32) {
      f16x8 af[2];
#pragma unroll
      for (int s = 0; s < 2; s++) {
        float4 a0 = *(const float4*)(arow[s] + kc + q * 8);
        float4 a1 = *(const float4*)(arow[s] + kc + q * 8 + 4);
        f16x8 v;
        v[0] = (_Float16)(a0.x * csc[s]);
        v[1] = (_Float16)(a0.y * csc[s]);
        v[2] = (_Float16)(a0.z * csc[s]);
        v[3] = (_Float16)(a0.w * csc[s]);
        v[4] = (_Float16)(a1.x * csc[s]);
        v[5] = (_Float16)(a1.y * csc[s]);
        v[6] = (_Float16)(a1.z * csc[s]);
        v[7] = (_Float16)(a1.w * csc[s]);
        af[s] = v;
      }
#pragma unroll
      for (int nt = 0; nt < 8; nt++) {
        f16x8 wf = *(const f16x8*)&Wt[nt * 16 + li][kc + q * 8];
        acc[0][nt] = __builtin_amdgcn_mfma_f32_16x16x32_f16(wf, af[0], acc[0][nt], 0, 0, 0);
        acc[1][nt] = __builtin_amdgcn_mfma_f32_16x16x32_f16(wf, af[1], acc[1][nt], 0, 0, 0);
      }
    }

#pragma unroll
    for (int s = 0; s < 2; s++) {
      if (!mok[s]) continue;
      size_t rb = (size_t)mrow[s] * 128;
#pragma unroll
      for (int nt = 0; nt < 8; nt++) {
        __half2 p0 = __floats2half2_rn(acc[s][nt][0], acc[s][nt][1]);
        __half2 p1 = __floats2half2_rn(acc[s][nt][2], acc[s][nt][3]);
        uint2 qv;
        qv.x = *(unsigned*)&p0;
        qv.y = *(unsigned*)&p1;
        *(uint2*)&out[rb + nt * 16 + q * 4] = qv;
      }
    }
  }
}

// ---------------- MFMA GEMM (R13 LDS form): out[m][n] = (sum_k A[m][k]*sc[m]*W[k][n]) -> fp16 ----------------

__device__ __forceinline__ f16x8 load_af(const __half* arow, int off, float csc) {
  f16x8 v = *(const f16x8*)(arow + off);
  _Float16 c = (_Float16)csc;
#pragma unroll
  for (int j = 0; j < 8; j++) v[j] = v[j] * c;
  return v;
}

__global__ __launch_bounds__(256) void k_gemm_mfma_h(const __half* __restrict__ A, const float* __restrict__ W,
                                                     const float* __restrict__ scale, __half* __restrict__ out, int N) {
  __shared__ _Float16 Wt[128][136];
  int t = threadIdx.x;
  {
    int nlow = t & 15;
    int kplow = t >> 4;
#pragma unroll
    for (int j = 0; j < 32; j++) {
      int n = nlow + 16 * (j & 7);
      int kp = kplow + 16 * (j >> 3);
      float w0 = W[(size_t)(2 * kp) * 128 + n];
      float w1 = W[(size_t)(2 * kp + 1) * 128 + n];
      __half2 h2 = __floats2half2_rn(w0, w1);
      *(__half2*)&Wt[n][2 * kp] = h2;
    }
  }
  __syncthreads();

  int wave = t >> 6;
  int lane = t & 63;
  int li = lane & 15;
  int q = lane >> 4;

#pragma unroll
  for (int s2 = 0; s2 < 2; s2++) {
    int m0 = (blockIdx.x * 2 + s2) * 128 + wave * 32;
    if (m0 >= N) break;

    int mrow[2];
    float csc[2];
    bool mok[2];
    const __half* arow[2];
#pragma unroll
    for (int s = 0; s < 2; s++) {
      mrow[s] = m0 + s * 16 + li;
      mok[s] = mrow[s] < N;
      csc[s] = mok[s] ? scale[mrow[s]] : 0.f;
      arow[s] = A + (size_t)(mok[s] ? mrow[s] : 0) * 128;
    }

    f32x4 acc[2][8];
#pragma unroll
    for (int s = 0; s < 2; s++)
#pragma unroll
      for (int nt = 0; nt < 8; nt++) acc[s][nt] = (f32x4){0.f, 0.f, 0.f, 0.f};

#pragma unroll
    for (int kc = 0; kc < 128; kc += 32) {
      f16x8 af[2];
#pragma unroll
      for (int s = 0; s < 2; s++) af[s] = load_af(arow[s], kc + q * 8, csc[s]);
#pragma unroll
      for (int nt = 0; nt < 8; nt++) {
        f16x8 wf = *(const f16x8*)&Wt[nt * 16 + li][kc + q * 8];
        acc[0][nt] = __builtin_amdgcn_mfma_f32_16x16x32_f16(wf, af[0], acc[0][nt], 0, 0, 0);
        acc[1][nt] = __builtin_amdgcn_mfma_f32_16x16x32_f16(wf, af[1], acc[1][nt], 0, 0, 0);
      }
    }

#pragma unroll
    for (int s = 0; s < 2; s++) {
      if (!mok[s]) continue;
      size_t rb = (size_t)mrow[s] * 128;
#pragma unroll
      for (int nt = 0; nt < 8; nt++) {
        __half2 p0 = __floats2half2_rn(acc[s][nt][0], acc[s][nt][1]);
        __half2 p1 = __floats2half2_rn(acc[s][nt][2], acc[s][nt][3]);
        uint2 qv;
        qv.x = *(unsigned*)&p0;
        qv.y = *(unsigned*)&p1;
        *(uint2*)&out[rb + nt * 16 + q * 4] = qv;
      }
    }
  }
}

// ---------------- Sparse aggregation: fp16 rows in, fp16 out (R9 shape: one 256-B row per wave,
//                  two 32-lane halves split the edge list; no LDS/barriers) ----------------

__device__ __forceinline__ void acc_pair(float4& a, uint2 qa, uint2 qb) {
  __half2 s0 = __hadd2(*(__half2*)&qa.x, *(__half2*)&qb.x);
  __half2 s1 = __hadd2(*(__half2*)&qa.y, *(__half2*)&qb.y);
  float2 f0 = __half22float2(s0);
  float2 f1 = __half22float2(s1);
  a.x += f0.x; a.y += f0.y; a.z += f1.x; a.w += f1.y;
}

__device__ __forceinline__ void acc_one(float4& a, uint2 q) {
  float2 f0 = __half22float2(*(__half2*)&q.x);
  float2 f1 = __half22float2(*(__half2*)&q.y);
  a.x += f0.x; a.y += f0.y; a.z += f1.x; a.w += f1.y;
}

__global__ __launch_bounds__(256) void k_aggregate_h(const __half* __restrict__ hin, const int* __restrict__ rp,
                                                     const int* __restrict__ ci, const float* __restrict__ c_dst,
                                                     const float* __restrict__ bias, __half* __restrict__ hout, int N) {
  int v = blockIdx.x * 4 + (threadIdx.x >> 6);
  if (v >= N) return;
  int half_id = (threadIdx.x >> 5) & 1;
  int f4 = (threadIdx.x & 31) * 4;
  const char* hb = (const char*)hin + f4 * 2;
  int p0 = rp[v], pe = rp[v + 1];
  int mid = p0 + ((pe - p0 + 1) >> 1);
  int p = half_id ? mid : p0;
  int pend = half_id ? pe : mid;
  float4 a0 = make_float4(0.f, 0.f, 0.f, 0.f);
  float4 a1 = make_float4(0.f, 0.f, 0.f, 0.f);
  float4 a2 = make_float4(0.f, 0.f, 0.f, 0.f);
  float4 a3 = make_float4(0.f, 0.f, 0.f, 0.f);
  for (; p + 7 < pend; p += 8) {
    int u0 = ci[p];
    int u1 = ci[p + 1];
    int u2 = ci[p + 2];
    int u3 = ci[p + 3];
    int u4 = ci[p + 4];
    int u5 = ci[p + 5];
    int u6 = ci[p + 6];
    int u7 = ci[p + 7];
    uint2 q0 = *(const uint2*)(hb + (size_t)(unsigned)u0);
    uint2 q1 = *(const uint2*)(hb + (size_t)(unsigned)u1);
    uint2 q2 = *(const uint2*)(hb + (size_t)(unsigned)u2);
    uint2 q3 = *(const uint2*)(hb + (size_t)(unsigned)u3);
    uint2 q4 = *(const uint2*)(hb + (size_t)(unsigned)u4);
    uint2 q5 = *(const uint2*)(hb + (size_t)(unsigned)u5);
    uint2 q6 = *(const uint2*)(hb + (size_t)(unsigned)u6);
    uint2 q7 = *(const uint2*)(hb + (size_t)(unsigned)u7);
    acc_pair(a0, q0, q1);
    acc_pair(a1, q2, q3);
    acc_pair(a2, q4, q5);
    acc_pair(a3, q6, q7);
  }
  for (; p + 1 < pend; p += 2) {
    int u0 = ci[p];
    int u1 = ci[p + 1];
    uint2 q0 = *(const uint2*)(hb + (size_t)(unsigned)u0);
    uint2 q1 = *(const uint2*)(hb + (size_t)(unsigned)u1);
    acc_pair(a0, q0, q1);
  }
  if (p < pend) {
    uint2 q = *(const uint2*)(hb + (size_t)(unsigned)ci[p]);
    acc_one(a0, q);
  }
  a0.x += a1.x; a0.y += a1.y; a0.z += a1.z; a0.w += a1.w;
  a2.x += a3.x; a2.y += a3.y; a2.z += a3.z; a2.w += a3.w;
  a0.x += a2.x; a0.y += a2.y; a0.z += a2.z; a0.w += a2.w;
  a0.x += __shfl_xor(a0.x, 32);
  a0.y += __shfl_xor(a0.y, 32);
  a0.z += __shfl_xor(a0.z, 32);
  a0.w += __shfl_xor(a0.w, 32);
  if (half_id == 0) {
    float cd = c_dst[v];
    float4 b = *(const float4*)&bias[f4];
    float4 o;
    o.x = fmaxf(fmaf(a0.x, cd, b.x), 0.f);
    o.y = fmaxf(fmaf(a0.y, cd, b.y), 0.f);
    o.z = fmaxf(fmaf(a0.z, cd, b.z), 0.f);
    o.w = fmaxf(fmaf(a0.w, cd, b.w), 0.f);
    __half2 p0h = __floats2half2_rn(o.x, o.y);
    __half2 p1h = __floats2half2_rn(o.z, o.w);
    uint2 qv;
    qv.x = *(unsigned*)&p0h;
    qv.y = *(unsigned*)&p1h;
    *(uint2*)&hout[(size_t)v * 128 + f4] = qv;
  }
}

// ---------------- Classifier (MFMA, R13 LDS form): out[N,47] = h @ Wc + bc, Wc hi+lo fp16 ----------------

__global__ __launch_bounds__(256) void k_classifier_mfma(const __half* __restrict__ h, const float* __restrict__ Wc,
                                                         const float* __restrict__ bc, float* __restrict__ out, int N) {
  __shared__ _Float16 Wt[96][136];   // rows 0..47: hi(Wc^T); rows 48..95: fp16 residual
  __shared__ float bs[48];
  int t = threadIdx.x;
  if (t < 47) bs[t] = bc[t];
  if (t == 47) bs[47] = 0.f;
  for (int i = t; i < 48 * 128; i += 256) {
    int n = i >> 7, k = i & 127;
    float w = (n < 47) ? Wc[(size_t)k * 47 + n] : 0.f;
    _Float16 hi = (_Float16)w;
    Wt[n][k] = hi;
    Wt[n + 48][k] = (_Float16)(w - (float)hi);
  }
  __syncthreads();

  int wave = t >> 6;
  int lane = t & 63;
  int li = lane & 15;
  int q = lane >> 4;

#pragma unroll
  for (int s2 = 0; s2 < 2; s2++) {
    int m0 = (blockIdx.x * 2 + s2) * 128 + wave * 32;
    if (m0 >= N) break;

    int mrow[2];
    bool mok[2];
    const __half* arow[2];
#pragma unroll
    for (int s = 0; s < 2; s++) {
      mrow[s] = m0 + s * 16 + li;
      mok[s] = mrow[s] < N;
      arow[s] = h + (size_t)(mok[s] ? mrow[s] : 0) * 128;
    }

    f32x4 acc[2][3];
#pragma unroll
    for (int s = 0; s < 2; s++)
#pragma unroll
      for (int nt = 0; nt < 3; nt++) acc[s][nt] = (f32x4){0.f, 0.f, 0.f, 0.f};

#pragma unroll
    for (int kc = 0; kc < 128; kc += 32) {
      f16x8 af[2];
#pragma unroll
      for (int s = 0; s < 2; s++) af[s] = *(const f16x8*)(arow[s] + kc + q * 8);
#pragma unroll
      for (int nt = 0; nt < 3; nt++) {
        f16x8 whi = *(const f16x8*)&Wt[nt * 16 + li][kc + q * 8];
        f16x8 wlo = *(const f16x8*)&Wt[48 + nt * 16 + li][kc + q * 8];
        acc[0][nt] = __builtin_amdgcn_mfma_f32_16x16x32_f16(whi, af[0], acc[0][nt], 0, 0, 0);
        acc[1][nt] = __builtin_amdgcn_mfma_f32_16x16x32_f16(whi, af[1], acc[1][nt], 0, 0, 0);
        acc[0][nt] = __builtin_amdgcn_mfma_f32_16x16x32_f16(wlo, af[0], acc[0][nt], 0, 0, 0);
        acc[1][nt] = __builtin_amdgcn_mfma_f32_16x16x32_f16(wlo, af[1], acc[1][nt], 0, 0, 0);
      }
    }

#pragma unroll
    for (int s = 0; s < 2; s++) {
      if (!mok[s]) continue;
      size_t rb = (size_t)mrow[s] * 47;
#pragma unroll
      for (int nt = 0; nt < 3; nt++) {
#pragma unroll
        for (int j = 0; j < 4; j++) {
          int c = nt * 16 + q * 4 + j;
          if (c < 47) out[rb + c] = acc[s][nt][j] + bs[c];
        }
      }
    }
  }
}

// ---------------- launch ----------------

extern "C" void kernel_launch(void* const* d_in, const int* in_sizes, int n_in,
                              void* d_out, int out_size, void* d_ws, size_t ws_size,
                              hipStream_t stream) {
  const float* x  = (const float*)d_in[0];
  const int* edges = (const int*)d_in[1];
  const float* W0 = (const float*)d_in[2];
  const float* b0 = (const float*)d_in[3];
  const float* W1 = (const float*)d_in[4];
  const float* b1 = (const float*)d_in[5];
  const float* Wc = (const float*)d_in[6];
  const float* bc = (const float*)d_in[7];
  float* out = (float*)d_out;

  int N = in_sizes[0] / 128;
  int E = in_sizes[1] / 2;
  const int* src = edges;
  const int* dst = edges + E;

  int NB = (N + ((1 << BSHIFT) - 1)) >> BSHIFT;   // 391
  int src_bits = 0;
  while ((1 << src_bits) < N) src_bits++;          // 17
  int per_blk = (E + PB - 1) / PB;
  int per_blk_d = (E + 1023) / 1024;

  char* base = (char*)d_ws;
  size_t off = 0;
  auto alloc = [&](size_t bytes) -> void* {
    void* p = base + off;
    off += (bytes + 255) & ~(size_t)255;
    return p;
  };
  float* c_src = (float*)alloc((size_t)N * 4);
  float* c_dst = (float*)alloc((size_t)N * 4);
  int* row_ptr = (int*)alloc((size_t)(N + 1) * 4);
  int* col_idx = (int*)alloc((size_t)E * 4);
  __half* h0h = (__half*)alloc((size_t)N * 128 * 2);   // GEMM outputs (fp16, 25.6 MB)
  __half* h1h = (__half*)alloc((size_t)N * 128 * 2);   // aggregate outputs (fp16, 25.6 MB)

  // build-time scratch carved out of h1h (dead until first k_aggregate writes it)
  char* hb = (char*)h1h;
  int* done = (int*)hb;                      hb += 256;                        // zeroed each run
  int* deg8 = (int*)hb;                      hb += (size_t)8 * N * 4;          // zeroed each run
  unsigned* ebuf = (unsigned*)hb;            hb += (size_t)E * 4;
  int* cntT = (int*)hb;                      hb += (size_t)NB * PB * 4;
  int* offsT = (int*)hb;                     hb += (size_t)NB * PB * 4;
  int* total = (int*)hb;                     hb += (size_t)NB * 4;
  int* bbase = (int*)hb;                     hb += (size_t)(NB + 1) * 4;

  hipMemsetAsync(done, 0, 256 + (size_t)8 * N * 4, stream);
  k_degsrc<<<1024, 256, 0, stream>>>(src, E, per_blk_d, N, deg8);
  k_count<<<PB, 256, 0, stream>>>(dst, E, per_blk, NB, cntT);
  k_scanblk<<<NB, 256, 0, stream>>>(cntT, offsT, total, NB, E, bbase, row_ptr, N, done);
  int cs_blocks = (N + 1023) / 1024;   // 98
  k_partition<<<PB + cs_blocks, 256, 0, stream>>>(src, dst, E, per_blk, NB, offsT, bbase,
                                                  ebuf, src_bits, deg8, c_src, N);

  int strips = (N + 127) / 128;
  int gblocks = (strips + 1) / 2;   // 391
  k_fin_gemm<<<NB + gblocks, 256, 0, stream>>>(ebuf, bbase, N, src_bits, NB,
                                               row_ptr, c_dst, col_idx,
                                               x, W0, c_src, h0h);
  k_aggregate_h<<<(N + 3) / 4, 256, 0, stream>>>(h0h, row_ptr, col_idx, c_dst, b0, h1h, N);
  k_gemm_mfma_h<<<gblocks, 256, 0, stream>>>(h1h, W1, c_src, h0h, N);
  k_aggregate_h<<<(N + 3) / 4, 256, 0, stream>>>(h0h, row_ptr, col_idx, c_dst, b1, h1h, N);
  k_classifier_mfma<<<gblocks, 256, 0, stream>>>(h1h, Wc, bc, out, N);
}

// Round 12
// 384.052 us; speedup vs baseline: 1.0710x; 1.0710x over previous
//
#include <hip/hip_runtime.h>
#include <hip/hip_fp16.h>

// GCN: h0 = relu(c_dst ⊙ Agg(c_src ⊙ x @ W0) + b0); h1 = same with W1; out = h1 @ Wc + bc
// R19: REVERT R18 (8-copy global histogram = +66 µs — random 4-B atomics cost is line-granular
//      RMW, copies don't help; src-side bucket chain measured ~free). Base = R17 (344.6, best).
//      NEW: kill k_scanblk + k_scantot via ATOMIC RESERVATION — k_count_res claims each block's
//      intra-bucket offset with atomicAdd on 391 padded (128-B-strided) bucket counters, and the
//      last block (done-flag) scans the totals -> bbase/sbase inline. Intra-bucket order becomes
//      block-arbitrary (proven harmless in R15: finalize re-sorts by node; summation order only
//      perturbs fp16 rounding). + 2-copy wave-parity LDS histograms in count. Launches 10 -> 9.

#define PB 256          // partition blocks
#define BSHIFT 8        // bucket = node >> 8 (256 nodes/bucket)

typedef _Float16 f16x8 __attribute__((ext_vector_type(8)));
typedef float f32x4 __attribute__((ext_vector_type(4)));

// ---------------- count + atomic-reserve offsets + inline total-scan (replaces count/scanblk/scantot) ----------------

__global__ __launch_bounds__(256) void k_count_res(const int* __restrict__ src, const int* __restrict__ dst,
                                                   int E, int per_blk, int NB,
                                                   int* __restrict__ offsT, int* __restrict__ offsT2,
                                                   int* __restrict__ gtot, int* __restrict__ gtot2,
                                                   int* __restrict__ bbase, int* __restrict__ sbase,
                                                   int* __restrict__ row_ptr, int N, int* __restrict__ done) {
  __shared__ int cnt[1024];    // [2][512] dst (wave-parity copies)
  __shared__ int cnt2[1024];   // [2][512] src
  __shared__ int amLast;
  int t = threadIdx.x, b = blockIdx.x;
  for (int i = t; i < 1024; i += 256) { cnt[i] = 0; cnt2[i] = 0; }
  __syncthreads();
  int w = (t >> 6) & 1;
  int e0 = b * per_blk, e1 = min(E, e0 + per_blk);
  for (int e = e0 + t; e < e1; e += 256) {
    atomicAdd(&cnt[w * 512 + (dst[e] >> BSHIFT)], 1);
    atomicAdd(&cnt2[w * 512 + (src[e] >> BSHIFT)], 1);
  }
  __syncthreads();
  for (int i = t; i < NB; i += 256) {
    int c = cnt[i] + cnt[512 + i];
    offsT[i * PB + b] = atomicAdd(&gtot[i * 32], c);       // 128-B stride: no line sharing
    int c2 = cnt2[i] + cnt2[512 + i];
    offsT2[i * PB + b] = atomicAdd(&gtot2[i * 32], c2);
  }
  __threadfence();
  __syncthreads();
  if (t == 0) amLast = (atomicAdd(done, 1) == (int)gridDim.x - 1);
  __syncthreads();
  if (!amLast) return;
  __threadfence();
  int* s = cnt;
  // scan gtot -> bbase (chunks of 256 with carry)
  int carry = 0;
  for (int base0 = 0; base0 < NB; base0 += 256) {
    int idx = base0 + t;
    int tv = (idx < NB) ? gtot[idx * 32] : 0;
    s[t] = tv;
    __syncthreads();
    for (int off = 1; off < 256; off <<= 1) {
      int x = (t >= off) ? s[t - off] : 0;
      __syncthreads();
      s[t] += x;
      __syncthreads();
    }
    if (idx < NB) bbase[idx] = carry + s[t] - tv;
    carry += s[255];
    __syncthreads();
  }
  // scan gtot2 -> sbase
  carry = 0;
  for (int base0 = 0; base0 < NB; base0 += 256) {
    int idx = base0 + t;
    int tv = (idx < NB) ? gtot2[idx * 32] : 0;
    s[t] = tv;
    __syncthreads();
    for (int off = 1; off < 256; off <<= 1) {
      int x = (t >= off) ? s[t - off] : 0;
      __syncthreads();
      s[t] += x;
      __syncthreads();
    }
    if (idx < NB) sbase[idx] = carry + s[t] - tv;
    carry += s[255];
    __syncthreads();
  }
  if (t == 0) {
    bbase[NB] = E;
    sbase[NB] = E;
    row_ptr[N] = E;
  }
}

// ---------------- Phase A: partition scatter (dst-sorted ebuf + src-bucketed srcrel bytes) ----------------

__global__ __launch_bounds__(256) void k_partition(const int* __restrict__ src, const int* __restrict__ dst,
                                                   int E, int per_blk, int NB,
                                                   const int* __restrict__ offsT, const int* __restrict__ bbase,
                                                   const int* __restrict__ offsT2, const int* __restrict__ sbase,
                                                   unsigned* __restrict__ ebuf, unsigned char* __restrict__ sbuf,
                                                   int src_bits) {
  __shared__ int cur[512];
  __shared__ int cur2[512];
  for (int i = threadIdx.x; i < NB; i += 256) {
    cur[i] = bbase[i] + offsT[i * PB + blockIdx.x];
    cur2[i] = sbase[i] + offsT2[i * PB + blockIdx.x];
  }
  __syncthreads();
  int e0 = blockIdx.x * per_blk, e1 = min(E, e0 + per_blk);
  for (int e = e0 + threadIdx.x; e < e1; e += 256) {
    int d = dst[e], s = src[e];
    int pos = atomicAdd(&cur[d >> BSHIFT], 1);
    ebuf[pos] = ((unsigned)(d & ((1 << BSHIFT) - 1)) << src_bits) | (unsigned)s;
    int pos2 = atomicAdd(&cur2[s >> BSHIFT], 1);
    sbuf[pos2] = (unsigned char)(s & ((1 << BSHIFT) - 1));
  }
}

// ---------------- per-src-bucket histogram -> c_src ----------------

__global__ __launch_bounds__(256) void k_finalize_src(const unsigned char* __restrict__ sbuf,
                                                      const int* __restrict__ sbase, int N,
                                                      float* __restrict__ c_src) {
  __shared__ int cnt[256];
  int b = blockIdx.x, t = threadIdx.x;
  cnt[t] = 0;
  __syncthreads();
  int q0 = sbase[b], q1 = sbase[b + 1];
  for (int i = q0 + t; i < q1; i += 256) atomicAdd(&cnt[sbuf[i]], 1);
  __syncthreads();
  int node = (b << BSHIFT) + t;
  if (node < N) c_src[node] = rsqrtf((float)max(cnt[t], 1));
}

// ---------------- fused: blocks [0,NB) = finalize_dst; blocks [NB,..) = gemm1 (x fp32) ----------------

__global__ __launch_bounds__(256) void k_fin_gemm(const unsigned* __restrict__ ebuf, const int* __restrict__ bbase,
                                                  int N, int src_bits, int NB,
                                                  int* __restrict__ row_ptr, float* __restrict__ c_dst,
                                                  int* __restrict__ col_idx,
                                                  const float* __restrict__ A, const float* __restrict__ W,
                                                  const float* __restrict__ scale, __half* __restrict__ out) {
  __shared__ _Float16 Wt[128][136];   // 34.8 KB; finalize path aliases the first 3 KB
  int t = threadIdx.x;

  if (blockIdx.x < NB) {
    int* cnt = (int*)&Wt[0][0];
    int* s = cnt + 256;
    int* cur = cnt + 512;
    int b = blockIdx.x;
    int r0 = bbase[b], r1 = bbase[b + 1];
    cnt[t] = 0;
    __syncthreads();
    for (int i = r0 + t; i < r1; i += 256) atomicAdd(&cnt[ebuf[i] >> src_bits], 1);
    __syncthreads();
    int v = cnt[t];
    s[t] = v;
    __syncthreads();
    for (int off = 1; off < 256; off <<= 1) {
      int x = (t >= off) ? s[t - off] : 0;
      __syncthreads();
      s[t] += x;
      __syncthreads();
    }
    int ex = s[t] - v;
    cur[t] = ex;
    int node = (b << BSHIFT) + t;
    if (node < N) {
      row_ptr[node] = r0 + ex;
      c_dst[node] = rsqrtf((float)max(v, 1));
    }
    __syncthreads();
    unsigned smask = (1u << src_bits) - 1u;
    for (int i = r0 + t; i < r1; i += 256) {
      unsigned e = ebuf[i];
      int pos = r0 + atomicAdd(&cur[e >> src_bits], 1);
      col_idx[pos] = (int)((e & smask) << 8);   // byte offset into fp16 h rows (256 B/row)
    }
    return;
  }

  // ---- gemm1 (R13 LDS form) ----
  int bid = blockIdx.x - NB;
  {
    int nlow = t & 15;
    int kplow = t >> 4;
#pragma unroll
    for (int j = 0; j < 32; j++) {
      int n = nlow + 16 * (j & 7);
      int kp = kplow + 16 * (j >> 3);
      float w0 = W[(size_t)(2 * kp) * 128 + n];
      float w1 = W[(size_t)(2 * kp + 1) * 128 + n];
      __half2 h2 = __floats2half2_rn(w0, w1);
      *(__half2*)&Wt[n][2 * kp] = h2;
    }
  }
  __syncthreads();

  int wave = t >> 6;
  int lane = t & 63;
  int li = lane & 15;
  int q = lane >> 4;

#pragma unroll
  for (int s2 = 0; s2 < 2; s2++) {
    int m0 = (bid * 2 + s2) * 128 + wave * 32;
    if (m0 >= N) break;

    int mrow[2];
    float csc[2];
    bool mok[2];
    const float* arow[2];
#pragma unroll
    for (int s = 0; s < 2; s++) {
      mrow[s] = m0 + s * 16 + li;
      mok[s] = mrow[s] < N;
      csc[s] = mok[s] ? scale[mrow[s]] : 0.f;
      arow[s] = A + (size_t)(mok[s] ? mrow[s] : 0) * 128;
    }

    f32x4 acc[2][8];
#pragma unroll
    for (int s = 0; s < 2; s++)
#pragma unroll
      for (int nt = 0; nt < 8; nt++) acc[s][nt] = (f32x4){0.f, 0.f, 0.f, 0.f};

#pragma unroll
    for (int kc = 0; kc < 128; kc += 32) {
      f16x8 af[2];
#pragma unroll
      for (int s = 0; s < 2; s++) {
        float4 a0 = *(const float4*)(arow[s] + kc + q * 8);
        float4 a1 = *(const float4*)(arow[s] + kc + q * 8 + 4);
        f16x8 v;
        v[0] = (_Float16)(a0.x * csc[s]);
        v[1] = (_Float16)(a0.y * csc[s]);
        v[2] = (_Float16)(a0.z * csc[s]);
        v[3] = (_Float16)(a0.w * csc[s]);
        v[4] = (_Float16)(a1.x * csc[s]);
        v[5] = (_Float16)(a1.y * csc[s]);
        v[6] = (_Float16)(a1.z * csc[s]);
        v[7] = (_Float16)(a1.w * csc[s]);
        af[s] = v;
      }
#pragma unroll
      for (int nt = 0; nt < 8; nt++) {
        f16x8 wf = *(const f16x8*)&Wt[nt * 16 + li][kc + q * 8];
        acc[0][nt] = __builtin_amdgcn_mfma_f32_16x16x32_f16(wf, af[0], acc[0][nt], 0, 0, 0);
        acc[1][nt] = __builtin_amdgcn_mfma_f32_16x16x32_f16(wf, af[1], acc[1][nt], 0, 0, 0);
      }
    }

#pragma unroll
    for (int s = 0; s < 2; s++) {
      if (!mok[s]) continue;
      size_t rb = (size_t)mrow[s] * 128;
#pragma unroll
      for (int nt = 0; nt < 8; nt++) {
        __half2 p0 = __floats2half2_rn(acc[s][nt][0], acc[s][nt][1]);
        __half2 p1 = __floats2half2_rn(acc[s][nt][2], acc[s][nt][3]);
        uint2 qv;
        qv.x = *(unsigned*)&p0;
        qv.y = *(unsigned*)&p1;
        *(uint2*)&out[rb + nt * 16 + q * 4] = qv;
      }
    }
  }
}

// ---------------- MFMA GEMM (R13 LDS form): out[m][n] = (sum_k A[m][k]*sc[m]*W[k][n]) -> fp16 ----------------

__device__ __forceinline__ f16x8 load_af(const __half* arow, int off, float csc) {
  f16x8 v = *(const f16x8*)(arow + off);
  _Float16 c = (_Float16)csc;
#pragma unroll
  for (int j = 0; j < 8; j++) v[j] = v[j] * c;
  return v;
}

__global__ __launch_bounds__(256) void k_gemm_mfma_h(const __half* __restrict__ A, const float* __restrict__ W,
                                                     const float* __restrict__ scale, __half* __restrict__ out, int N) {
  __shared__ _Float16 Wt[128][136];
  int t = threadIdx.x;
  {
    int nlow = t & 15;
    int kplow = t >> 4;
#pragma unroll
    for (int j = 0; j < 32; j++) {
      int n = nlow + 16 * (j & 7);
      int kp = kplow + 16 * (j >> 3);
      float w0 = W[(size_t)(2 * kp) * 128 + n];
      float w1 = W[(size_t)(2 * kp + 1) * 128 + n];
      __half2 h2 = __floats2half2_rn(w0, w1);
      *(__half2*)&Wt[n][2 * kp] = h2;
    }
  }
  __syncthreads();

  int wave = t >> 6;
  int lane = t & 63;
  int li = lane & 15;
  int q = lane >> 4;

#pragma unroll
  for (int s2 = 0; s2 < 2; s2++) {
    int m0 = (blockIdx.x * 2 + s2) * 128 + wave * 32;
    if (m0 >= N) break;

    int mrow[2];
    float csc[2];
    bool mok[2];
    const __half* arow[2];
#pragma unroll
    for (int s = 0; s < 2; s++) {
      mrow[s] = m0 + s * 16 + li;
      mok[s] = mrow[s] < N;
      csc[s] = mok[s] ? scale[mrow[s]] : 0.f;
      arow[s] = A + (size_t)(mok[s] ? mrow[s] : 0) * 128;
    }

    f32x4 acc[2][8];
#pragma unroll
    for (int s = 0; s < 2; s++)
#pragma unroll
      for (int nt = 0; nt < 8; nt++) acc[s][nt] = (f32x4){0.f, 0.f, 0.f, 0.f};

#pragma unroll
    for (int kc = 0; kc < 128; kc += 32) {
      f16x8 af[2];
#pragma unroll
      for (int s = 0; s < 2; s++) af[s] = load_af(arow[s], kc + q * 8, csc[s]);
#pragma unroll
      for (int nt = 0; nt < 8; nt++) {
        f16x8 wf = *(const f16x8*)&Wt[nt * 16 + li][kc + q * 8];
        acc[0][nt] = __builtin_amdgcn_mfma_f32_16x16x32_f16(wf, af[0], acc[0][nt], 0, 0, 0);
        acc[1][nt] = __builtin_amdgcn_mfma_f32_16x16x32_f16(wf, af[1], acc[1][nt], 0, 0, 0);
      }
    }

#pragma unroll
    for (int s = 0; s < 2; s++) {
      if (!mok[s]) continue;
      size_t rb = (size_t)mrow[s] * 128;
#pragma unroll
      for (int nt = 0; nt < 8; nt++) {
        __half2 p0 = __floats2half2_rn(acc[s][nt][0], acc[s][nt][1]);
        __half2 p1 = __floats2half2_rn(acc[s][nt][2], acc[s][nt][3]);
        uint2 qv;
        qv.x = *(unsigned*)&p0;
        qv.y = *(unsigned*)&p1;
        *(uint2*)&out[rb + nt * 16 + q * 4] = qv;
      }
    }
  }
}

// ---------------- Sparse aggregation: fp16 rows in, fp16 out (R9 shape: one 256-B row per wave,
//                  two 32-lane halves split the edge list; no LDS/barriers) ----------------

__device__ __forceinline__ void acc_pair(float4& a, uint2 qa, uint2 qb) {
  __half2 s0 = __hadd2(*(__half2*)&qa.x, *(__half2*)&qb.x);
  __half2 s1 = __hadd2(*(__half2*)&qa.y, *(__half2*)&qb.y);
  float2 f0 = __half22float2(s0);
  float2 f1 = __half22float2(s1);
  a.x += f0.x; a.y += f0.y; a.z += f1.x; a.w += f1.y;
}

__device__ __forceinline__ void acc_one(float4& a, uint2 q) {
  float2 f0 = __half22float2(*(__half2*)&q.x);
  float2 f1 = __half22float2(*(__half2*)&q.y);
  a.x += f0.x; a.y += f0.y; a.z += f1.x; a.w += f1.y;
}

__global__ __launch_bounds__(256) void k_aggregate_h(const __half* __restrict__ hin, const int* __restrict__ rp,
                                                     const int* __restrict__ ci, const float* __restrict__ c_dst,
                                                     const float* __restrict__ bias, __half* __restrict__ hout, int N) {
  int v = blockIdx.x * 4 + (threadIdx.x >> 6);
  if (v >= N) return;
  int half_id = (threadIdx.x >> 5) & 1;
  int f4 = (threadIdx.x & 31) * 4;
  const char* hb = (const char*)hin + f4 * 2;
  int p0 = rp[v], pe = rp[v + 1];
  int mid = p0 + ((pe - p0 + 1) >> 1);
  int p = half_id ? mid : p0;
  int pend = half_id ? pe : mid;
  float4 a0 = make_float4(0.f, 0.f, 0.f, 0.f);
  float4 a1 = make_float4(0.f, 0.f, 0.f, 0.f);
  float4 a2 = make_float4(0.f, 0.f, 0.f, 0.f);
  float4 a3 = make_float4(0.f, 0.f, 0.f, 0.f);
  for (; p + 7 < pend; p += 8) {
    int u0 = ci[p];
    int u1 = ci[p + 1];
    int u2 = ci[p + 2];
    int u3 = ci[p + 3];
    int u4 = ci[p + 4];
    int u5 = ci[p + 5];
    int u6 = ci[p + 6];
    int u7 = ci[p + 7];
    uint2 q0 = *(const uint2*)(hb + (size_t)(unsigned)u0);
    uint2 q1 = *(const uint2*)(hb + (size_t)(unsigned)u1);
    uint2 q2 = *(const uint2*)(hb + (size_t)(unsigned)u2);
    uint2 q3 = *(const uint2*)(hb + (size_t)(unsigned)u3);
    uint2 q4 = *(const uint2*)(hb + (size_t)(unsigned)u4);
    uint2 q5 = *(const uint2*)(hb + (size_t)(unsigned)u5);
    uint2 q6 = *(const uint2*)(hb + (size_t)(unsigned)u6);
    uint2 q7 = *(const uint2*)(hb + (size_t)(unsigned)u7);
    acc_pair(a0, q0, q1);
    acc_pair(a1, q2, q3);
    acc_pair(a2, q4, q5);
    acc_pair(a3, q6, q7);
  }
  for (; p + 1 < pend; p += 2) {
    int u0 = ci[p];
    int u1 = ci[p + 1];
    uint2 q0 = *(const uint2*)(hb + (size_t)(unsigned)u0);
    uint2 q1 = *(const uint2*)(hb + (size_t)(unsigned)u1);
    acc_pair(a0, q0, q1);
  }
  if (p < pend) {
    uint2 q = *(const uint2*)(hb + (size_t)(unsigned)ci[p]);
    acc_one(a0, q);
  }
  a0.x += a1.x; a0.y += a1.y; a0.z += a1.z; a0.w += a1.w;
  a2.x += a3.x; a2.y += a3.y; a2.z += a3.z; a2.w += a3.w;
  a0.x += a2.x; a0.y += a2.y; a0.z += a2.z; a0.w += a2.w;
  a0.x += __shfl_xor(a0.x, 32);
  a0.y += __shfl_xor(a0.y, 32);
  a0.z += __shfl_xor(a0.z, 32);
  a0.w += __shfl_xor(a0.w, 32);
  if (half_id == 0) {
    float cd = c_dst[v];
    float4 b = *(const float4*)&bias[f4];
    float4 o;
    o.x = fmaxf(fmaf(a0.x, cd, b.x), 0.f);
    o.y = fmaxf(fmaf(a0.y, cd, b.y), 0.f);
    o.z = fmaxf(fmaf(a0.z, cd, b.z), 0.f);
    o.w = fmaxf(fmaf(a0.w, cd, b.w), 0.f);
    __half2 p0h = __floats2half2_rn(o.x, o.y);
    __half2 p1h = __floats2half2_rn(o.z, o.w);
    uint2 qv;
    qv.x = *(unsigned*)&p0h;
    qv.y = *(unsigned*)&p1h;
    *(uint2*)&hout[(size_t)v * 128 + f4] = qv;
  }
}

// ---------------- Classifier (MFMA, R13 LDS form): out[N,47] = h @ Wc + bc, Wc hi+lo fp16 ----------------

__global__ __launch_bounds__(256) void k_classifier_mfma(const __half* __restrict__ h, const float* __restrict__ Wc,
                                                         const float* __restrict__ bc, float* __restrict__ out, int N) {
  __shared__ _Float16 Wt[96][136];   // rows 0..47: hi(Wc^T); rows 48..95: fp16 residual
  __shared__ float bs[48];
  int t = threadIdx.x;
  if (t < 47) bs[t] = bc[t];
  if (t == 47) bs[47] = 0.f;
  for (int i = t; i < 48 * 128; i += 256) {
    int n = i >> 7, k = i & 127;
    float w = (n < 47) ? Wc[(size_t)k * 47 + n] : 0.f;
    _Float16 hi = (_Float16)w;
    Wt[n][k] = hi;
    Wt[n + 48][k] = (_Float16)(w - (float)hi);
  }
  __syncthreads();

  int wave = t >> 6;
  int lane = t & 63;
  int li = lane & 15;
  int q = lane >> 4;

#pragma unroll
  for (int s2 = 0; s2 < 2; s2++) {
    int m0 = (blockIdx.x * 2 + s2) * 128 + wave * 32;
    if (m0 >= N) break;

    int mrow[2];
    bool mok[2];
    const __half* arow[2];
#pragma unroll
    for (int s = 0; s < 2; s++) {
      mrow[s] = m0 + s * 16 + li;
      mok[s] = mrow[s] < N;
      arow[s] = h + (size_t)(mok[s] ? mrow[s] : 0) * 128;
    }

    f32x4 acc[2][3];
#pragma unroll
    for (int s = 0; s < 2; s++)
#pragma unroll
      for (int nt = 0; nt < 3; nt++) acc[s][nt] = (f32x4){0.f, 0.f, 0.f, 0.f};

#pragma unroll
    for (int kc = 0; kc < 128; kc += 32) {
      f16x8 af[2];
#pragma unroll
      for (int s = 0; s < 2; s++) af[s] = *(const f16x8*)(arow[s] + kc + q * 8);
#pragma unroll
      for (int nt = 0; nt < 3; nt++) {
        f16x8 whi = *(const f16x8*)&Wt[nt * 16 + li][kc + q * 8];
        f16x8 wlo = *(const f16x8*)&Wt[48 + nt * 16 + li][kc + q * 8];
        acc[0][nt] = __builtin_amdgcn_mfma_f32_16x16x32_f16(whi, af[0], acc[0][nt], 0, 0, 0);
        acc[1][nt] = __builtin_amdgcn_mfma_f32_16x16x32_f16(whi, af[1], acc[1][nt], 0, 0, 0);
        acc[0][nt] = __builtin_amdgcn_mfma_f32_16x16x32_f16(wlo, af[0], acc[0][nt], 0, 0, 0);
        acc[1][nt] = __builtin_amdgcn_mfma_f32_16x16x32_f16(wlo, af[1], acc[1][nt], 0, 0, 0);
      }
    }

#pragma unroll
    for (int s = 0; s < 2; s++) {
      if (!mok[s]) continue;
      size_t rb = (size_t)mrow[s] * 47;
#pragma unroll
      for (int nt = 0; nt < 3; nt++) {
#pragma unroll
        for (int j = 0; j < 4; j++) {
          int c = nt * 16 + q * 4 + j;
          if (c < 47) out[rb + c] = acc[s][nt][j] + bs[c];
        }
      }
    }
  }
}

// ---------------- launch ----------------

extern "C" void kernel_launch(void* const* d_in, const int* in_sizes, int n_in,
                              void* d_out, int out_size, void* d_ws, size_t ws_size,
                              hipStream_t stream) {
  const float* x  = (const float*)d_in[0];
  const int* edges = (const int*)d_in[1];
  const float* W0 = (const float*)d_in[2];
  const float* b0 = (const float*)d_in[3];
  const float* W1 = (const float*)d_in[4];
  const float* b1 = (const float*)d_in[5];
  const float* Wc = (const float*)d_in[6];
  const float* bc = (const float*)d_in[7];
  float* out = (float*)d_out;

  int N = in_sizes[0] / 128;
  int E = in_sizes[1] / 2;
  const int* src = edges;
  const int* dst = edges + E;

  int NB = (N + ((1 << BSHIFT) - 1)) >> BSHIFT;   // 391 (<=512 required)
  int src_bits = 0;
  while ((1 << src_bits) < N) src_bits++;          // 17
  int per_blk = (E + PB - 1) / PB;

  char* base = (char*)d_ws;
  size_t off = 0;
  auto alloc = [&](size_t bytes) -> void* {
    void* p = base + off;
    off += (bytes + 255) & ~(size_t)255;
    return p;
  };
  float* c_src = (float*)alloc((size_t)N * 4);
  float* c_dst = (float*)alloc((size_t)N * 4);
  int* row_ptr = (int*)alloc((size_t)(N + 1) * 4);
  int* col_idx = (int*)alloc((size_t)E * 4);
  __half* h0h = (__half*)alloc((size_t)N * 128 * 2);   // GEMM outputs (fp16, 25.6 MB)
  __half* h1h = (__half*)alloc((size_t)N * 128 * 2);   // aggregate outputs (fp16, 25.6 MB)

  // build-time scratch carved out of h1h (dead until first k_aggregate writes it)
  char* hb = (char*)h1h;
  int* done = (int*)hb;                      hb += 256;                         // zeroed
  int* gtot = (int*)hb;                      hb += (size_t)NB * 32 * 4;         // zeroed (128-B strided)
  int* gtot2 = (int*)hb;                     hb += (size_t)NB * 32 * 4;         // zeroed
  unsigned* ebuf = (unsigned*)hb;            hb += (size_t)E * 4;
  unsigned char* sbuf = (unsigned char*)hb;  hb += ((size_t)E + 255) & ~(size_t)255;
  int* offsT = (int*)hb;                     hb += (size_t)NB * PB * 4;
  int* offsT2 = (int*)hb;                    hb += (size_t)NB * PB * 4;
  int* bbase = (int*)hb;                     hb += (size_t)(NB + 1) * 4;
  int* sbase = (int*)hb;                     hb += (size_t)(NB + 1) * 4;

  size_t zbytes = 256 + (size_t)2 * NB * 32 * 4;
  hipMemsetAsync(done, 0, zbytes, stream);
  k_count_res<<<PB, 256, 0, stream>>>(src, dst, E, per_blk, NB, offsT, offsT2, gtot, gtot2,
                                      bbase, sbase, row_ptr, N, done);
  k_partition<<<PB, 256, 0, stream>>>(src, dst, E, per_blk, NB, offsT, bbase, offsT2, sbase,
                                      ebuf, sbuf, src_bits);
  k_finalize_src<<<NB, 256, 0, stream>>>(sbuf, sbase, N, c_src);

  int strips = (N + 127) / 128;
  int gblocks = (strips + 1) / 2;   // 391
  k_fin_gemm<<<NB + gblocks, 256, 0, stream>>>(ebuf, bbase, N, src_bits, NB,
                                               row_ptr, c_dst, col_idx,
                                               x, W0, c_src, h0h);
  k_aggregate_h<<<(N + 3) / 4, 256, 0, stream>>>(h0h, row_ptr, col_idx, c_dst, b0, h1h, N);
  k_gemm_mfma_h<<<gblocks, 256, 0, stream>>>(h1h, W1, c_src, h0h, N);
  k_aggregate_h<<<(N + 3) / 4, 256, 0, stream>>>(h0h, row_ptr, col_idx, c_dst, b1, h1h, N);
  k_classifier_mfma<<<gblocks, 256, 0, stream>>>(h1h, Wc, bc, out, N);
}

// Round 13
// 334.789 us; speedup vs baseline: 1.2285x; 1.1471x over previous
//
#include <hip/hip_runtime.h>
#include <hip/hip_fp16.h>

// GCN: h0 = relu(c_dst ⊙ Agg(c_src ⊙ x @ W0) + b0); h1 = same with W1; out = h1 @ Wc + bc
// R20: REVERT R19 (atomic-reservation count = 384 µs; its counters showed the real story:
//      edge-pass LDS-histogram kernels at PB=256 run ~66 µs at VALUBusy 0.5% / Occ 9% — pure
//      load-latency stall, no ILP; R13/R17's k_count was hiding just under the 65 µs cutoff).
//      Base = R17 exactly (344.6 best). ONE change: 4x-unroll the edge loops in k_count and
//      k_partition (batch 4 loads -> 4 atomic groups) = 4x memory-level parallelism per wave.
//      Same traffic, same semantics (atomics commutative; intra-bucket order arbitrary, proven
//      harmless R15/R19 — finalize re-sorts by node; fp16 sum order within absmax margin).

#define PB 256          // partition blocks
#define BSHIFT 8        // bucket = node >> 8 (256 nodes/bucket)

typedef _Float16 f16x8 __attribute__((ext_vector_type(8)));
typedef float f32x4 __attribute__((ext_vector_type(4)));

// ---------------- Phase A: bucket counts (src and dst), 4x-unrolled edge loop ----------------

__global__ __launch_bounds__(256) void k_count(const int* __restrict__ src, const int* __restrict__ dst,
                                               int E, int per_blk, int NB,
                                               int* __restrict__ cntT, int* __restrict__ cntT2) {
  __shared__ int cnt[512];
  __shared__ int cnt2[512];
  for (int i = threadIdx.x; i < 512; i += 256) { cnt[i] = 0; cnt2[i] = 0; }
  __syncthreads();
  int e0 = blockIdx.x * per_blk, e1 = min(E, e0 + per_blk);
  int e = e0 + threadIdx.x;
  for (; e + 768 < e1; e += 1024) {
    int d0 = dst[e],       s0 = src[e];
    int d1 = dst[e + 256], s1 = src[e + 256];
    int d2 = dst[e + 512], s2 = src[e + 512];
    int d3 = dst[e + 768], s3 = src[e + 768];
    atomicAdd(&cnt[d0 >> BSHIFT], 1);
    atomicAdd(&cnt2[s0 >> BSHIFT], 1);
    atomicAdd(&cnt[d1 >> BSHIFT], 1);
    atomicAdd(&cnt2[s1 >> BSHIFT], 1);
    atomicAdd(&cnt[d2 >> BSHIFT], 1);
    atomicAdd(&cnt2[s2 >> BSHIFT], 1);
    atomicAdd(&cnt[d3 >> BSHIFT], 1);
    atomicAdd(&cnt2[s3 >> BSHIFT], 1);
  }
  for (; e < e1; e += 256) {
    atomicAdd(&cnt[dst[e] >> BSHIFT], 1);
    atomicAdd(&cnt2[src[e] >> BSHIFT], 1);
  }
  __syncthreads();
  for (int i = threadIdx.x; i < NB; i += 256) {
    cntT[i * PB + blockIdx.x] = cnt[i];
    cntT2[i * PB + blockIdx.x] = cnt2[i];
  }
}

// exclusive scan of each bucket's 256 per-block counts (works on concatenated tables)
__global__ __launch_bounds__(256) void k_scanblk(const int* __restrict__ cntT, int* __restrict__ offsT,
                                                 int* __restrict__ total) {
  __shared__ int s[256];
  int b = blockIdx.x, t = threadIdx.x;
  int v = cntT[b * PB + t];
  s[t] = v;
  __syncthreads();
  for (int off = 1; off < 256; off <<= 1) {
    int x = (t >= off) ? s[t - off] : 0;
    __syncthreads();
    s[t] += x;
    __syncthreads();
  }
  offsT[b * PB + t] = s[t] - v;
  if (t == 255) total[b] = s[255];
}

// block 0: scan dst totals -> bbase (+row_ptr[N]); block 1: scan src totals -> sbase
__global__ __launch_bounds__(512) void k_scantot(const int* __restrict__ total, int NB, int E,
                                                 int* __restrict__ bbase, int* __restrict__ sbase,
                                                 int* __restrict__ row_ptr, int N) {
  __shared__ int s[512];
  int t = threadIdx.x;
  const int* tot = (blockIdx.x == 0) ? total : total + NB;
  int* obase = (blockIdx.x == 0) ? bbase : sbase;
  int v = (t < NB) ? tot[t] : 0;
  s[t] = v;
  __syncthreads();
  for (int off = 1; off < 512; off <<= 1) {
    int x = (t >= off) ? s[t - off] : 0;
    __syncthreads();
    s[t] += x;
    __syncthreads();
  }
  if (t < NB) obase[t] = s[t] - v;
  if (t == 0) obase[NB] = E;
  if (blockIdx.x == 0 && t == 0) row_ptr[N] = E;
}

// ---------------- Phase A: partition scatter (dst-sorted ebuf + src-bucketed srcrel bytes),
//                  4x-unrolled edge loop ----------------

__global__ __launch_bounds__(256) void k_partition(const int* __restrict__ src, const int* __restrict__ dst,
                                                   int E, int per_blk, int NB,
                                                   const int* __restrict__ offsT, const int* __restrict__ bbase,
                                                   const int* __restrict__ offsT2, const int* __restrict__ sbase,
                                                   unsigned* __restrict__ ebuf, unsigned char* __restrict__ sbuf,
                                                   int src_bits) {
  __shared__ int cur[512];
  __shared__ int cur2[512];
  for (int i = threadIdx.x; i < NB; i += 256) {
    cur[i] = bbase[i] + offsT[i * PB + blockIdx.x];
    cur2[i] = sbase[i] + offsT2[i * PB + blockIdx.x];
  }
  __syncthreads();
  unsigned lmask = (1u << BSHIFT) - 1u;
  int e0 = blockIdx.x * per_blk, e1 = min(E, e0 + per_blk);
  int e = e0 + threadIdx.x;
  for (; e + 768 < e1; e += 1024) {
    int d0 = dst[e],       s0 = src[e];
    int d1 = dst[e + 256], s1 = src[e + 256];
    int d2 = dst[e + 512], s2 = src[e + 512];
    int d3 = dst[e + 768], s3 = src[e + 768];
    int p0 = atomicAdd(&cur[d0 >> BSHIFT], 1);
    ebuf[p0] = ((unsigned)(d0 & lmask) << src_bits) | (unsigned)s0;
    int q0 = atomicAdd(&cur2[s0 >> BSHIFT], 1);
    sbuf[q0] = (unsigned char)(s0 & lmask);
    int p1 = atomicAdd(&cur[d1 >> BSHIFT], 1);
    ebuf[p1] = ((unsigned)(d1 & lmask) << src_bits) | (unsigned)s1;
    int q1 = atomicAdd(&cur2[s1 >> BSHIFT], 1);
    sbuf[q1] = (unsigned char)(s1 & lmask);
    int p2 = atomicAdd(&cur[d2 >> BSHIFT], 1);
    ebuf[p2] = ((unsigned)(d2 & lmask) << src_bits) | (unsigned)s2;
    int q2 = atomicAdd(&cur2[s2 >> BSHIFT], 1);
    sbuf[q2] = (unsigned char)(s2 & lmask);
    int p3 = atomicAdd(&cur[d3 >> BSHIFT], 1);
    ebuf[p3] = ((unsigned)(d3 & lmask) << src_bits) | (unsigned)s3;
    int q3 = atomicAdd(&cur2[s3 >> BSHIFT], 1);
    sbuf[q3] = (unsigned char)(s3 & lmask);
  }
  for (; e < e1; e += 256) {
    int d = dst[e], s = src[e];
    int pos = atomicAdd(&cur[d >> BSHIFT], 1);
    ebuf[pos] = ((unsigned)(d & lmask) << src_bits) | (unsigned)s;
    int pos2 = atomicAdd(&cur2[s >> BSHIFT], 1);
    sbuf[pos2] = (unsigned char)(s & lmask);
  }
}

// ---------------- per-src-bucket histogram -> c_src (runs before the fused launch) ----------------

__global__ __launch_bounds__(256) void k_finalize_src(const unsigned char* __restrict__ sbuf,
                                                      const int* __restrict__ sbase, int N,
                                                      float* __restrict__ c_src) {
  __shared__ int cnt[256];
  int b = blockIdx.x, t = threadIdx.x;
  cnt[t] = 0;
  __syncthreads();
  int q0 = sbase[b], q1 = sbase[b + 1];
  for (int i = q0 + t; i < q1; i += 256) atomicAdd(&cnt[sbuf[i]], 1);
  __syncthreads();
  int node = (b << BSHIFT) + t;
  if (node < N) c_src[node] = rsqrtf((float)max(cnt[t], 1));
}

// ---------------- fused: blocks [0,NB) = finalize_dst; blocks [NB,..) = gemm1 (x fp32) ----------------

__global__ __launch_bounds__(256) void k_fin_gemm(const unsigned* __restrict__ ebuf, const int* __restrict__ bbase,
                                                  int N, int src_bits, int NB,
                                                  int* __restrict__ row_ptr, float* __restrict__ c_dst,
                                                  int* __restrict__ col_idx,
                                                  const float* __restrict__ A, const float* __restrict__ W,
                                                  const float* __restrict__ scale, __half* __restrict__ out) {
  __shared__ _Float16 Wt[128][136];   // 34.8 KB; finalize path aliases the first 3 KB
  int t = threadIdx.x;

  if (blockIdx.x < NB) {
    int* cnt = (int*)&Wt[0][0];
    int* s = cnt + 256;
    int* cur = cnt + 512;
    int b = blockIdx.x;
    int r0 = bbase[b], r1 = bbase[b + 1];
    cnt[t] = 0;
    __syncthreads();
    for (int i = r0 + t; i < r1; i += 256) atomicAdd(&cnt[ebuf[i] >> src_bits], 1);
    __syncthreads();
    int v = cnt[t];
    s[t] = v;
    __syncthreads();
    for (int off = 1; off < 256; off <<= 1) {
      int x = (t >= off) ? s[t - off] : 0;
      __syncthreads();
      s[t] += x;
      __syncthreads();
    }
    int ex = s[t] - v;
    cur[t] = ex;
    int node = (b << BSHIFT) + t;
    if (node < N) {
      row_ptr[node] = r0 + ex;
      c_dst[node] = rsqrtf((float)max(v, 1));
    }
    __syncthreads();
    unsigned smask = (1u << src_bits) - 1u;
    for (int i = r0 + t; i < r1; i += 256) {
      unsigned e = ebuf[i];
      int pos = r0 + atomicAdd(&cur[e >> src_bits], 1);
      col_idx[pos] = (int)((e & smask) << 8);   // byte offset into fp16 h rows (256 B/row)
    }
    return;
  }

  // ---- gemm1 (R13 LDS form) ----
  int bid = blockIdx.x - NB;
  {
    int nlow = t & 15;
    int kplow = t >> 4;
#pragma unroll
    for (int j = 0; j < 32; j++) {
      int n = nlow + 16 * (j & 7);
      int kp = kplow + 16 * (j >> 3);
      float w0 = W[(size_t)(2 * kp) * 128 + n];
      float w1 = W[(size_t)(2 * kp + 1) * 128 + n];
      __half2 h2 = __floats2half2_rn(w0, w1);
      *(__half2*)&Wt[n][2 * kp] = h2;
    }
  }
  __syncthreads();

  int wave = t >> 6;
  int lane = t & 63;
  int li = lane & 15;
  int q = lane >> 4;

#pragma unroll
  for (int s2 = 0; s2 < 2; s2++) {
    int m0 = (bid * 2 + s2) * 128 + wave * 32;
    if (m0 >= N) break;

    int mrow[2];
    float csc[2];
    bool mok[2];
    const float* arow[2];
#pragma unroll
    for (int s = 0; s < 2; s++) {
      mrow[s] = m0 + s * 16 + li;
      mok[s] = mrow[s] < N;
      csc[s] = mok[s] ? scale[mrow[s]] : 0.f;
      arow[s] = A + (size_t)(mok[s] ? mrow[s] : 0) * 128;
    }

    f32x4 acc[2][8];
#pragma unroll
    for (int s = 0; s < 2; s++)
#pragma unroll
      for (int nt = 0; nt < 8; nt++) acc[s][nt] = (f32x4){0.f, 0.f, 0.f, 0.f};

#pragma unroll
    for (int kc = 0; kc < 128; kc += 32) {
      f16x8 af[2];
#pragma unroll
      for (int s = 0; s < 2; s++) {
        float4 a0 = *(const float4*)(arow[s] + kc + q * 8);
        float4 a1 = *(const float4*)(arow[s] + kc + q * 8 + 4);
        f16x8 v;
        v[0] = (_Float16)(a0.x * csc[s]);
        v[1] = (_Float16)(a0.y * csc[s]);
        v[2] = (_Float16)(a0.z * csc[s]);
        v[3] = (_Float16)(a0.w * csc[s]);
        v[4] = (_Float16)(a1.x * csc[s]);
        v[5] = (_Float16)(a1.y * csc[s]);
        v[6] = (_Float16)(a1.z * csc[s]);
        v[7] = (_Float16)(a1.w * csc[s]);
        af[s] = v;
      }
#pragma unroll
      for (int nt = 0; nt < 8; nt++) {
        f16x8 wf = *(const f16x8*)&Wt[nt * 16 + li][kc + q * 8];
        acc[0][nt] = __builtin_amdgcn_mfma_f32_16x16x32_f16(wf, af[0], acc[0][nt], 0, 0, 0);
        acc[1][nt] = __builtin_amdgcn_mfma_f32_16x16x32_f16(wf, af[1], acc[1][nt], 0, 0, 0);
      }
    }

#pragma unroll
    for (int s = 0; s < 2; s++) {
      if (!mok[s]) continue;
      size_t rb = (size_t)mrow[s] * 128;
#pragma unroll
      for (int nt = 0; nt < 8; nt++) {
        __half2 p0 = __floats2half2_rn(acc[s][nt][0], acc[s][nt][1]);
        __half2 p1 = __floats2half2_rn(acc[s][nt][2], acc[s][nt][3]);
        uint2 qv;
        qv.x = *(unsigned*)&p0;
        qv.y = *(unsigned*)&p1;
        *(uint2*)&out[rb + nt * 16 + q * 4] = qv;
      }
    }
  }
}

// ---------------- MFMA GEMM (R13 LDS form): out[m][n] = (sum_k A[m][k]*sc[m]*W[k][n]) -> fp16 ----------------

__device__ __forceinline__ f16x8 load_af(const __half* arow, int off, float csc) {
  f16x8 v = *(const f16x8*)(arow + off);
  _Float16 c = (_Float16)csc;
#pragma unroll
  for (int j = 0; j < 8; j++) v[j] = v[j] * c;
  return v;
}

__global__ __launch_bounds__(256) void k_gemm_mfma_h(const __half* __restrict__ A, const float* __restrict__ W,
                                                     const float* __restrict__ scale, __half* __restrict__ out, int N) {
  __shared__ _Float16 Wt[128][136];
  int t = threadIdx.x;
  {
    int nlow = t & 15;
    int kplow = t >> 4;
#pragma unroll
    for (int j = 0; j < 32; j++) {
      int n = nlow + 16 * (j & 7);
      int kp = kplow + 16 * (j >> 3);
      float w0 = W[(size_t)(2 * kp) * 128 + n];
      float w1 = W[(size_t)(2 * kp + 1) * 128 + n];
      __half2 h2 = __floats2half2_rn(w0, w1);
      *(__half2*)&Wt[n][2 * kp] = h2;
    }
  }
  __syncthreads();

  int wave = t >> 6;
  int lane = t & 63;
  int li = lane & 15;
  int q = lane >> 4;

#pragma unroll
  for (int s2 = 0; s2 < 2; s2++) {
    int m0 = (blockIdx.x * 2 + s2) * 128 + wave * 32;
    if (m0 >= N) break;

    int mrow[2];
    float csc[2];
    bool mok[2];
    const __half* arow[2];
#pragma unroll
    for (int s = 0; s < 2; s++) {
      mrow[s] = m0 + s * 16 + li;
      mok[s] = mrow[s] < N;
      csc[s] = mok[s] ? scale[mrow[s]] : 0.f;
      arow[s] = A + (size_t)(mok[s] ? mrow[s] : 0) * 128;
    }

    f32x4 acc[2][8];
#pragma unroll
    for (int s = 0; s < 2; s++)
#pragma unroll
      for (int nt = 0; nt < 8; nt++) acc[s][nt] = (f32x4){0.f, 0.f, 0.f, 0.f};

#pragma unroll
    for (int kc = 0; kc < 128; kc += 32) {
      f16x8 af[2];
#pragma unroll
      for (int s = 0; s < 2; s++) af[s] = load_af(arow[s], kc + q * 8, csc[s]);
#pragma unroll
      for (int nt = 0; nt < 8; nt++) {
        f16x8 wf = *(const f16x8*)&Wt[nt * 16 + li][kc + q * 8];
        acc[0][nt] = __builtin_amdgcn_mfma_f32_16x16x32_f16(wf, af[0], acc[0][nt], 0, 0, 0);
        acc[1][nt] = __builtin_amdgcn_mfma_f32_16x16x32_f16(wf, af[1], acc[1][nt], 0, 0, 0);
      }
    }

#pragma unroll
    for (int s = 0; s < 2; s++) {
      if (!mok[s]) continue;
      size_t rb = (size_t)mrow[s] * 128;
#pragma unroll
      for (int nt = 0; nt < 8; nt++) {
        __half2 p0 = __floats2half2_rn(acc[s][nt][0], acc[s][nt][1]);
        __half2 p1 = __floats2half2_rn(acc[s][nt][2], acc[s][nt][3]);
        uint2 qv;
        qv.x = *(unsigned*)&p0;
        qv.y = *(unsigned*)&p1;
        *(uint2*)&out[rb + nt * 16 + q * 4] = qv;
      }
    }
  }
}

// ---------------- Sparse aggregation: fp16 rows in, fp16 out (R9 shape: one 256-B row per wave,
//                  two 32-lane halves split the edge list; no LDS/barriers) ----------------

__device__ __forceinline__ void acc_pair(float4& a, uint2 qa, uint2 qb) {
  __half2 s0 = __hadd2(*(__half2*)&qa.x, *(__half2*)&qb.x);
  __half2 s1 = __hadd2(*(__half2*)&qa.y, *(__half2*)&qb.y);
  float2 f0 = __half22float2(s0);
  float2 f1 = __half22float2(s1);
  a.x += f0.x; a.y += f0.y; a.z += f1.x; a.w += f1.y;
}

__device__ __forceinline__ void acc_one(float4& a, uint2 q) {
  float2 f0 = __half22float2(*(__half2*)&q.x);
  float2 f1 = __half22float2(*(__half2*)&q.y);
  a.x += f0.x; a.y += f0.y; a.z += f1.x; a.w += f1.y;
}

__global__ __launch_bounds__(256) void k_aggregate_h(const __half* __restrict__ hin, const int* __restrict__ rp,
                                                     const int* __restrict__ ci, const float* __restrict__ c_dst,
                                                     const float* __restrict__ bias, __half* __restrict__ hout, int N) {
  int v = blockIdx.x * 4 + (threadIdx.x >> 6);
  if (v >= N) return;
  int half_id = (threadIdx.x >> 5) & 1;
  int f4 = (threadIdx.x & 31) * 4;
  const char* hb = (const char*)hin + f4 * 2;
  int p0 = rp[v], pe = rp[v + 1];
  int mid = p0 + ((pe - p0 + 1) >> 1);
  int p = half_id ? mid : p0;
  int pend = half_id ? pe : mid;
  float4 a0 = make_float4(0.f, 0.f, 0.f, 0.f);
  float4 a1 = make_float4(0.f, 0.f, 0.f, 0.f);
  float4 a2 = make_float4(0.f, 0.f, 0.f, 0.f);
  float4 a3 = make_float4(0.f, 0.f, 0.f, 0.f);
  for (; p + 7 < pend; p += 8) {
    int u0 = ci[p];
    int u1 = ci[p + 1];
    int u2 = ci[p + 2];
    int u3 = ci[p + 3];
    int u4 = ci[p + 4];
    int u5 = ci[p + 5];
    int u6 = ci[p + 6];
    int u7 = ci[p + 7];
    uint2 q0 = *(const uint2*)(hb + (size_t)(unsigned)u0);
    uint2 q1 = *(const uint2*)(hb + (size_t)(unsigned)u1);
    uint2 q2 = *(const uint2*)(hb + (size_t)(unsigned)u2);
    uint2 q3 = *(const uint2*)(hb + (size_t)(unsigned)u3);
    uint2 q4 = *(const uint2*)(hb + (size_t)(unsigned)u4);
    uint2 q5 = *(const uint2*)(hb + (size_t)(unsigned)u5);
    uint2 q6 = *(const uint2*)(hb + (size_t)(unsigned)u6);
    uint2 q7 = *(const uint2*)(hb + (size_t)(unsigned)u7);
    acc_pair(a0, q0, q1);
    acc_pair(a1, q2, q3);
    acc_pair(a2, q4, q5);
    acc_pair(a3, q6, q7);
  }
  for (; p + 1 < pend; p += 2) {
    int u0 = ci[p];
    int u1 = ci[p + 1];
    uint2 q0 = *(const uint2*)(hb + (size_t)(unsigned)u0);
    uint2 q1 = *(const uint2*)(hb + (size_t)(unsigned)u1);
    acc_pair(a0, q0, q1);
  }
  if (p < pend) {
    uint2 q = *(const uint2*)(hb + (size_t)(unsigned)ci[p]);
    acc_one(a0, q);
  }
  a0.x += a1.x; a0.y += a1.y; a0.z += a1.z; a0.w += a1.w;
  a2.x += a3.x; a2.y += a3.y; a2.z += a3.z; a2.w += a3.w;
  a0.x += a2.x; a0.y += a2.y; a0.z += a2.z; a0.w += a2.w;
  a0.x += __shfl_xor(a0.x, 32);
  a0.y += __shfl_xor(a0.y, 32);
  a0.z += __shfl_xor(a0.z, 32);
  a0.w += __shfl_xor(a0.w, 32);
  if (half_id == 0) {
    float cd = c_dst[v];
    float4 b = *(const float4*)&bias[f4];
    float4 o;
    o.x = fmaxf(fmaf(a0.x, cd, b.x), 0.f);
    o.y = fmaxf(fmaf(a0.y, cd, b.y), 0.f);
    o.z = fmaxf(fmaf(a0.z, cd, b.z), 0.f);
    o.w = fmaxf(fmaf(a0.w, cd, b.w), 0.f);
    __half2 p0h = __floats2half2_rn(o.x, o.y);
    __half2 p1h = __floats2half2_rn(o.z, o.w);
    uint2 qv;
    qv.x = *(unsigned*)&p0h;
    qv.y = *(unsigned*)&p1h;
    *(uint2*)&hout[(size_t)v * 128 + f4] = qv;
  }
}

// ---------------- Classifier (MFMA, R13 LDS form): out[N,47] = h @ Wc + bc, Wc hi+lo fp16 ----------------

__global__ __launch_bounds__(256) void k_classifier_mfma(const __half* __restrict__ h, const float* __restrict__ Wc,
                                                         const float* __restrict__ bc, float* __restrict__ out, int N) {
  __shared__ _Float16 Wt[96][136];   // rows 0..47: hi(Wc^T); rows 48..95: fp16 residual
  __shared__ float bs[48];
  int t = threadIdx.x;
  if (t < 47) bs[t] = bc[t];
  if (t == 47) bs[47] = 0.f;
  for (int i = t; i < 48 * 128; i += 256) {
    int n = i >> 7, k = i & 127;
    float w = (n < 47) ? Wc[(size_t)k * 47 + n] : 0.f;
    _Float16 hi = (_Float16)w;
    Wt[n][k] = hi;
    Wt[n + 48][k] = (_Float16)(w - (float)hi);
  }
  __syncthreads();

  int wave = t >> 6;
  int lane = t & 63;
  int li = lane & 15;
  int q = lane >> 4;

#pragma unroll
  for (int s2 = 0; s2 < 2; s2++) {
    int m0 = (blockIdx.x * 2 + s2) * 128 + wave * 32;
    if (m0 >= N) break;

    int mrow[2];
    bool mok[2];
    const __half* arow[2];
#pragma unroll
    for (int s = 0; s < 2; s++) {
      mrow[s] = m0 + s * 16 + li;
      mok[s] = mrow[s] < N;
      arow[s] = h + (size_t)(mok[s] ? mrow[s] : 0) * 128;
    }

    f32x4 acc[2][3];
#pragma unroll
    for (int s = 0; s < 2; s++)
#pragma unroll
      for (int nt = 0; nt < 3; nt++) acc[s][nt] = (f32x4){0.f, 0.f, 0.f, 0.f};

#pragma unroll
    for (int kc = 0; kc < 128; kc += 32) {
      f16x8 af[2];
#pragma unroll
      for (int s = 0; s < 2; s++) af[s] = *(const f16x8*)(arow[s] + kc + q * 8);
#pragma unroll
      for (int nt = 0; nt < 3; nt++) {
        f16x8 whi = *(const f16x8*)&Wt[nt * 16 + li][kc + q * 8];
        f16x8 wlo = *(const f16x8*)&Wt[48 + nt * 16 + li][kc + q * 8];
        acc[0][nt] = __builtin_amdgcn_mfma_f32_16x16x32_f16(whi, af[0], acc[0][nt], 0, 0, 0);
        acc[1][nt] = __builtin_amdgcn_mfma_f32_16x16x32_f16(whi, af[1], acc[1][nt], 0, 0, 0);
        acc[0][nt] = __builtin_amdgcn_mfma_f32_16x16x32_f16(wlo, af[0], acc[0][nt], 0, 0, 0);
        acc[1][nt] = __builtin_amdgcn_mfma_f32_16x16x32_f16(wlo, af[1], acc[1][nt], 0, 0, 0);
      }
    }

#pragma unroll
    for (int s = 0; s < 2; s++) {
      if (!mok[s]) continue;
      size_t rb = (size_t)mrow[s] * 47;
#pragma unroll
      for (int nt = 0; nt < 3; nt++) {
#pragma unroll
        for (int j = 0; j < 4; j++) {
          int c = nt * 16 + q * 4 + j;
          if (c < 47) out[rb + c] = acc[s][nt][j] + bs[c];
        }
      }
    }
  }
}

// ---------------- launch ----------------

extern "C" void kernel_launch(void* const* d_in, const int* in_sizes, int n_in,
                              void* d_out, int out_size, void* d_ws, size_t ws_size,
                              hipStream_t stream) {
  const float* x  = (const float*)d_in[0];
  const int* edges = (const int*)d_in[1];
  const float* W0 = (const float*)d_in[2];
  const float* b0 = (const float*)d_in[3];
  const float* W1 = (const float*)d_in[4];
  const float* b1 = (const float*)d_in[5];
  const float* Wc = (const float*)d_in[6];
  const float* bc = (const float*)d_in[7];
  float* out = (float*)d_out;

  int N = in_sizes[0] / 128;
  int E = in_sizes[1] / 2;
  const int* src = edges;
  const int* dst = edges + E;

  int NB = (N + ((1 << BSHIFT) - 1)) >> BSHIFT;   // 391 (<=512 required)
  int src_bits = 0;
  while ((1 << src_bits) < N) src_bits++;          // 17
  int per_blk = (E + PB - 1) / PB;

  char* base = (char*)d_ws;
  size_t off = 0;
  auto alloc = [&](size_t bytes) -> void* {
    void* p = base + off;
    off += (bytes + 255) & ~(size_t)255;
    return p;
  };
  float* c_src = (float*)alloc((size_t)N * 4);
  float* c_dst = (float*)alloc((size_t)N * 4);
  int* row_ptr = (int*)alloc((size_t)(N + 1) * 4);
  int* col_idx = (int*)alloc((size_t)E * 4);
  __half* h0h = (__half*)alloc((size_t)N * 128 * 2);   // GEMM outputs (fp16, 25.6 MB)
  __half* h1h = (__half*)alloc((size_t)N * 128 * 2);   // aggregate outputs (fp16, 25.6 MB)

  // build-time scratch carved out of h1h (dead until first k_aggregate writes it)
  char* hb = (char*)h1h;
  unsigned* ebuf = (unsigned*)hb;            hb += (size_t)E * 4;
  unsigned char* sbuf = (unsigned char*)hb;  hb += ((size_t)E + 255) & ~(size_t)255;
  int* cntT = (int*)hb;                      hb += (size_t)2 * NB * PB * 4;   // [dst | src]
  int* offsT = (int*)hb;                     hb += (size_t)2 * NB * PB * 4;
  int* total = (int*)hb;                     hb += (size_t)2 * NB * 4;
  int* bbase = (int*)hb;                     hb += (size_t)(NB + 1) * 4;
  int* sbase = (int*)hb;                     hb += (size_t)(NB + 1) * 4;
  int* cntT2 = cntT + (size_t)NB * PB;
  int* offsT2 = offsT + (size_t)NB * PB;

  k_count<<<PB, 256, 0, stream>>>(src, dst, E, per_blk, NB, cntT, cntT2);
  k_scanblk<<<2 * NB, 256, 0, stream>>>(cntT, offsT, total);
  k_scantot<<<2, 512, 0, stream>>>(total, NB, E, bbase, sbase, row_ptr, N);
  k_partition<<<PB, 256, 0, stream>>>(src, dst, E, per_blk, NB, offsT, bbase, offsT2, sbase,
                                      ebuf, sbuf, src_bits);
  k_finalize_src<<<NB, 256, 0, stream>>>(sbuf, sbase, N, c_src);

  int strips = (N + 127) / 128;
  int gblocks = (strips + 1) / 2;   // 391
  // fused: finalize_dst (blocks 0..NB-1) overlapped with gemm1 (blocks NB..NB+gblocks-1)
  k_fin_gemm<<<NB + gblocks, 256, 0, stream>>>(ebuf, bbase, N, src_bits, NB,
                                               row_ptr, c_dst, col_idx,
                                               x, W0, c_src, h0h);
  k_aggregate_h<<<(N + 3) / 4, 256, 0, stream>>>(h0h, row_ptr, col_idx, c_dst, b0, h1h, N);
  k_gemm_mfma_h<<<gblocks, 256, 0, stream>>>(h1h, W1, c_src, h0h, N);
  k_aggregate_h<<<(N + 3) / 4, 256, 0, stream>>>(h0h, row_ptr, col_idx, c_dst, b1, h1h, N);
  k_classifier_mfma<<<gblocks, 256, 0, stream>>>(h1h, Wc, bc, out, N);
}

// Round 14
// 330.734 us; speedup vs baseline: 1.2436x; 1.0123x over previous
//
#include <hip/hip_runtime.h>
#include <hip/hip_fp16.h>

// GCN: h0 = relu(c_dst ⊙ Agg(c_src ⊙ x @ W0) + b0); h1 = same with W1; out = h1 @ Wc + bc
// R21: R20 (334.8, best) confirmed the preproc-ILP theory (+9.8 from 4x-unroll). Deeper:
//      k_count 8x-unroll + 2-copy wave-parity LDS histograms (halves atomic serialization);
//      k_partition 8x-unroll; finalize_src byte-histogram and fin_gemm finalize histogram+
//      scatter loops 4x-unrolled. All semantics-preserving (commutative atomics; intra-bucket
//      order arbitrary — proven R15/R19/R20, absmax pinned at 2^-10). Aggregates (65.5 µs MLP
//      floor), gemms, classifier, fin_gemm overlap: byte-identical to R20.

#define PB 256          // partition blocks
#define BSHIFT 8        // bucket = node >> 8 (256 nodes/bucket)

typedef _Float16 f16x8 __attribute__((ext_vector_type(8)));
typedef float f32x4 __attribute__((ext_vector_type(4)));

// ---------------- Phase A: bucket counts (src and dst), 8x-unrolled + 2-copy histograms ----------------

__global__ __launch_bounds__(256) void k_count(const int* __restrict__ src, const int* __restrict__ dst,
                                               int E, int per_blk, int NB,
                                               int* __restrict__ cntT, int* __restrict__ cntT2) {
  __shared__ int cnt[1024];    // [2][512] dst, wave-parity copies
  __shared__ int cnt2[1024];   // [2][512] src
  for (int i = threadIdx.x; i < 1024; i += 256) { cnt[i] = 0; cnt2[i] = 0; }
  __syncthreads();
  int w = ((threadIdx.x >> 6) & 1) << 9;   // 0 or 512
  int e0 = blockIdx.x * per_blk, e1 = min(E, e0 + per_blk);
  int e = e0 + threadIdx.x;
  for (; e + 1792 < e1; e += 2048) {
    int d0 = dst[e],        s0 = src[e];
    int d1 = dst[e + 256],  s1 = src[e + 256];
    int d2 = dst[e + 512],  s2 = src[e + 512];
    int d3 = dst[e + 768],  s3 = src[e + 768];
    int d4 = dst[e + 1024], s4 = src[e + 1024];
    int d5 = dst[e + 1280], s5 = src[e + 1280];
    int d6 = dst[e + 1536], s6 = src[e + 1536];
    int d7 = dst[e + 1792], s7 = src[e + 1792];
    atomicAdd(&cnt[w + (d0 >> BSHIFT)], 1);
    atomicAdd(&cnt2[w + (s0 >> BSHIFT)], 1);
    atomicAdd(&cnt[w + (d1 >> BSHIFT)], 1);
    atomicAdd(&cnt2[w + (s1 >> BSHIFT)], 1);
    atomicAdd(&cnt[w + (d2 >> BSHIFT)], 1);
    atomicAdd(&cnt2[w + (s2 >> BSHIFT)], 1);
    atomicAdd(&cnt[w + (d3 >> BSHIFT)], 1);
    atomicAdd(&cnt2[w + (s3 >> BSHIFT)], 1);
    atomicAdd(&cnt[w + (d4 >> BSHIFT)], 1);
    atomicAdd(&cnt2[w + (s4 >> BSHIFT)], 1);
    atomicAdd(&cnt[w + (d5 >> BSHIFT)], 1);
    atomicAdd(&cnt2[w + (s5 >> BSHIFT)], 1);
    atomicAdd(&cnt[w + (d6 >> BSHIFT)], 1);
    atomicAdd(&cnt2[w + (s6 >> BSHIFT)], 1);
    atomicAdd(&cnt[w + (d7 >> BSHIFT)], 1);
    atomicAdd(&cnt2[w + (s7 >> BSHIFT)], 1);
  }
  for (; e < e1; e += 256) {
    atomicAdd(&cnt[w + (dst[e] >> BSHIFT)], 1);
    atomicAdd(&cnt2[w + (src[e] >> BSHIFT)], 1);
  }
  __syncthreads();
  for (int i = threadIdx.x; i < NB; i += 256) {
    cntT[i * PB + blockIdx.x] = cnt[i] + cnt[512 + i];
    cntT2[i * PB + blockIdx.x] = cnt2[i] + cnt2[512 + i];
  }
}

// exclusive scan of each bucket's 256 per-block counts (works on concatenated tables)
__global__ __launch_bounds__(256) void k_scanblk(const int* __restrict__ cntT, int* __restrict__ offsT,
                                                 int* __restrict__ total) {
  __shared__ int s[256];
  int b = blockIdx.x, t = threadIdx.x;
  int v = cntT[b * PB + t];
  s[t] = v;
  __syncthreads();
  for (int off = 1; off < 256; off <<= 1) {
    int x = (t >= off) ? s[t - off] : 0;
    __syncthreads();
    s[t] += x;
    __syncthreads();
  }
  offsT[b * PB + t] = s[t] - v;
  if (t == 255) total[b] = s[255];
}

// block 0: scan dst totals -> bbase (+row_ptr[N]); block 1: scan src totals -> sbase
__global__ __launch_bounds__(512) void k_scantot(const int* __restrict__ total, int NB, int E,
                                                 int* __restrict__ bbase, int* __restrict__ sbase,
                                                 int* __restrict__ row_ptr, int N) {
  __shared__ int s[512];
  int t = threadIdx.x;
  const int* tot = (blockIdx.x == 0) ? total : total + NB;
  int* obase = (blockIdx.x == 0) ? bbase : sbase;
  int v = (t < NB) ? tot[t] : 0;
  s[t] = v;
  __syncthreads();
  for (int off = 1; off < 512; off <<= 1) {
    int x = (t >= off) ? s[t - off] : 0;
    __syncthreads();
    s[t] += x;
    __syncthreads();
  }
  if (t < NB) obase[t] = s[t] - v;
  if (t == 0) obase[NB] = E;
  if (blockIdx.x == 0 && t == 0) row_ptr[N] = E;
}

// ---------------- Phase A: partition scatter, 8x-unrolled ----------------

__global__ __launch_bounds__(256) void k_partition(const int* __restrict__ src, const int* __restrict__ dst,
                                                   int E, int per_blk, int NB,
                                                   const int* __restrict__ offsT, const int* __restrict__ bbase,
                                                   const int* __restrict__ offsT2, const int* __restrict__ sbase,
                                                   unsigned* __restrict__ ebuf, unsigned char* __restrict__ sbuf,
                                                   int src_bits) {
  __shared__ int cur[512];
  __shared__ int cur2[512];
  for (int i = threadIdx.x; i < NB; i += 256) {
    cur[i] = bbase[i] + offsT[i * PB + blockIdx.x];
    cur2[i] = sbase[i] + offsT2[i * PB + blockIdx.x];
  }
  __syncthreads();
  unsigned lmask = (1u << BSHIFT) - 1u;
  int e0 = blockIdx.x * per_blk, e1 = min(E, e0 + per_blk);
  int e = e0 + threadIdx.x;
  for (; e + 1792 < e1; e += 2048) {
    int d0 = dst[e],        s0 = src[e];
    int d1 = dst[e + 256],  s1 = src[e + 256];
    int d2 = dst[e + 512],  s2 = src[e + 512];
    int d3 = dst[e + 768],  s3 = src[e + 768];
    int d4 = dst[e + 1024], s4 = src[e + 1024];
    int d5 = dst[e + 1280], s5 = src[e + 1280];
    int d6 = dst[e + 1536], s6 = src[e + 1536];
    int d7 = dst[e + 1792], s7 = src[e + 1792];
    int p0 = atomicAdd(&cur[d0 >> BSHIFT], 1);
    ebuf[p0] = ((unsigned)(d0 & lmask) << src_bits) | (unsigned)s0;
    int q0 = atomicAdd(&cur2[s0 >> BSHIFT], 1);
    sbuf[q0] = (unsigned char)(s0 & lmask);
    int p1 = atomicAdd(&cur[d1 >> BSHIFT], 1);
    ebuf[p1] = ((unsigned)(d1 & lmask) << src_bits) | (unsigned)s1;
    int q1 = atomicAdd(&cur2[s1 >> BSHIFT], 1);
    sbuf[q1] = (unsigned char)(s1 & lmask);
    int p2 = atomicAdd(&cur[d2 >> BSHIFT], 1);
    ebuf[p2] = ((unsigned)(d2 & lmask) << src_bits) | (unsigned)s2;
    int q2 = atomicAdd(&cur2[s2 >> BSHIFT], 1);
    sbuf[q2] = (unsigned char)(s2 & lmask);
    int p3 = atomicAdd(&cur[d3 >> BSHIFT], 1);
    ebuf[p3] = ((unsigned)(d3 & lmask) << src_bits) | (unsigned)s3;
    int q3 = atomicAdd(&cur2[s3 >> BSHIFT], 1);
    sbuf[q3] = (unsigned char)(s3 & lmask);
    int p4 = atomicAdd(&cur[d4 >> BSHIFT], 1);
    ebuf[p4] = ((unsigned)(d4 & lmask) << src_bits) | (unsigned)s4;
    int q4 = atomicAdd(&cur2[s4 >> BSHIFT], 1);
    sbuf[q4] = (unsigned char)(s4 & lmask);
    int p5 = atomicAdd(&cur[d5 >> BSHIFT], 1);
    ebuf[p5] = ((unsigned)(d5 & lmask) << src_bits) | (unsigned)s5;
    int q5 = atomicAdd(&cur2[s5 >> BSHIFT], 1);
    sbuf[q5] = (unsigned char)(s5 & lmask);
    int p6 = atomicAdd(&cur[d6 >> BSHIFT], 1);
    ebuf[p6] = ((unsigned)(d6 & lmask) << src_bits) | (unsigned)s6;
    int q6 = atomicAdd(&cur2[s6 >> BSHIFT], 1);
    sbuf[q6] = (unsigned char)(s6 & lmask);
    int p7 = atomicAdd(&cur[d7 >> BSHIFT], 1);
    ebuf[p7] = ((unsigned)(d7 & lmask) << src_bits) | (unsigned)s7;
    int q7 = atomicAdd(&cur2[s7 >> BSHIFT], 1);
    sbuf[q7] = (unsigned char)(s7 & lmask);
  }
  for (; e < e1; e += 256) {
    int d = dst[e], s = src[e];
    int pos = atomicAdd(&cur[d >> BSHIFT], 1);
    ebuf[pos] = ((unsigned)(d & lmask) << src_bits) | (unsigned)s;
    int pos2 = atomicAdd(&cur2[s >> BSHIFT], 1);
    sbuf[pos2] = (unsigned char)(s & lmask);
  }
}

// ---------------- per-src-bucket histogram -> c_src, 4x-unrolled ----------------

__global__ __launch_bounds__(256) void k_finalize_src(const unsigned char* __restrict__ sbuf,
                                                      const int* __restrict__ sbase, int N,
                                                      float* __restrict__ c_src) {
  __shared__ int cnt[256];
  int b = blockIdx.x, t = threadIdx.x;
  cnt[t] = 0;
  __syncthreads();
  int q0 = sbase[b], q1 = sbase[b + 1];
  int i = q0 + t;
  for (; i + 768 < q1; i += 1024) {
    unsigned char b0 = sbuf[i];
    unsigned char b1 = sbuf[i + 256];
    unsigned char b2 = sbuf[i + 512];
    unsigned char b3 = sbuf[i + 768];
    atomicAdd(&cnt[b0], 1);
    atomicAdd(&cnt[b1], 1);
    atomicAdd(&cnt[b2], 1);
    atomicAdd(&cnt[b3], 1);
  }
  for (; i < q1; i += 256) atomicAdd(&cnt[sbuf[i]], 1);
  __syncthreads();
  int node = (b << BSHIFT) + t;
  if (node < N) c_src[node] = rsqrtf((float)max(cnt[t], 1));
}

// ---------------- fused: blocks [0,NB) = finalize_dst (4x-unrolled); blocks [NB,..) = gemm1 ----------------

__global__ __launch_bounds__(256) void k_fin_gemm(const unsigned* __restrict__ ebuf, const int* __restrict__ bbase,
                                                  int N, int src_bits, int NB,
                                                  int* __restrict__ row_ptr, float* __restrict__ c_dst,
                                                  int* __restrict__ col_idx,
                                                  const float* __restrict__ A, const float* __restrict__ W,
                                                  const float* __restrict__ scale, __half* __restrict__ out) {
  __shared__ _Float16 Wt[128][136];   // 34.8 KB; finalize path aliases the first 3 KB
  int t = threadIdx.x;

  if (blockIdx.x < NB) {
    int* cnt = (int*)&Wt[0][0];
    int* s = cnt + 256;
    int* cur = cnt + 512;
    int b = blockIdx.x;
    int r0 = bbase[b], r1 = bbase[b + 1];
    cnt[t] = 0;
    __syncthreads();
    int i = r0 + t;
    for (; i + 768 < r1; i += 1024) {
      unsigned ea = ebuf[i];
      unsigned eb = ebuf[i + 256];
      unsigned ec = ebuf[i + 512];
      unsigned ed = ebuf[i + 768];
      atomicAdd(&cnt[ea >> src_bits], 1);
      atomicAdd(&cnt[eb >> src_bits], 1);
      atomicAdd(&cnt[ec >> src_bits], 1);
      atomicAdd(&cnt[ed >> src_bits], 1);
    }
    for (; i < r1; i += 256) atomicAdd(&cnt[ebuf[i] >> src_bits], 1);
    __syncthreads();
    int v = cnt[t];
    s[t] = v;
    __syncthreads();
    for (int off = 1; off < 256; off <<= 1) {
      int x = (t >= off) ? s[t - off] : 0;
      __syncthreads();
      s[t] += x;
      __syncthreads();
    }
    int ex = s[t] - v;
    cur[t] = ex;
    int node = (b << BSHIFT) + t;
    if (node < N) {
      row_ptr[node] = r0 + ex;
      c_dst[node] = rsqrtf((float)max(v, 1));
    }
    __syncthreads();
    unsigned smask = (1u << src_bits) - 1u;
    i = r0 + t;
    for (; i + 768 < r1; i += 1024) {
      unsigned ea = ebuf[i];
      unsigned eb = ebuf[i + 256];
      unsigned ec = ebuf[i + 512];
      unsigned ed = ebuf[i + 768];
      int pa = r0 + atomicAdd(&cur[ea >> src_bits], 1);
      col_idx[pa] = (int)((ea & smask) << 8);
      int pb = r0 + atomicAdd(&cur[eb >> src_bits], 1);
      col_idx[pb] = (int)((eb & smask) << 8);
      int pc = r0 + atomicAdd(&cur[ec >> src_bits], 1);
      col_idx[pc] = (int)((ec & smask) << 8);
      int pd = r0 + atomicAdd(&cur[ed >> src_bits], 1);
      col_idx[pd] = (int)((ed & smask) << 8);
    }
    for (; i < r1; i += 256) {
      unsigned e = ebuf[i];
      int pos = r0 + atomicAdd(&cur[e >> src_bits], 1);
      col_idx[pos] = (int)((e & smask) << 8);   // byte offset into fp16 h rows (256 B/row)
    }
    return;
  }

  // ---- gemm1 (R13 LDS form) ----
  int bid = blockIdx.x - NB;
  {
    int nlow = t & 15;
    int kplow = t >> 4;
#pragma unroll
    for (int j = 0; j < 32; j++) {
      int n = nlow + 16 * (j & 7);
      int kp = kplow + 16 * (j >> 3);
      float w0 = W[(size_t)(2 * kp) * 128 + n];
      float w1 = W[(size_t)(2 * kp + 1) * 128 + n];
      __half2 h2 = __floats2half2_rn(w0, w1);
      *(__half2*)&Wt[n][2 * kp] = h2;
    }
  }
  __syncthreads();

  int wave = t >> 6;
  int lane = t & 63;
  int li = lane & 15;
  int q = lane >> 4;

#pragma unroll
  for (int s2 = 0; s2 < 2; s2++) {
    int m0 = (bid * 2 + s2) * 128 + wave * 32;
    if (m0 >= N) break;

    int mrow[2];
    float csc[2];
    bool mok[2];
    const float* arow[2];
#pragma unroll
    for (int s = 0; s < 2; s++) {
      mrow[s] = m0 + s * 16 + li;
      mok[s] = mrow[s] < N;
      csc[s] = mok[s] ? scale[mrow[s]] : 0.f;
      arow[s] = A + (size_t)(mok[s] ? mrow[s] : 0) * 128;
    }

    f32x4 acc[2][8];
#pragma unroll
    for (int s = 0; s < 2; s++)
#pragma unroll
      for (int nt = 0; nt < 8; nt++) acc[s][nt] = (f32x4){0.f, 0.f, 0.f, 0.f};

#pragma unroll
    for (int kc = 0; kc < 128; kc += 32) {
      f16x8 af[2];
#pragma unroll
      for (int s = 0; s < 2; s++) {
        float4 a0 = *(const float4*)(arow[s] + kc + q * 8);
        float4 a1 = *(const float4*)(arow[s] + kc + q * 8 + 4);
        f16x8 v;
        v[0] = (_Float16)(a0.x * csc[s]);
        v[1] = (_Float16)(a0.y * csc[s]);
        v[2] = (_Float16)(a0.z * csc[s]);
        v[3] = (_Float16)(a0.w * csc[s]);
        v[4] = (_Float16)(a1.x * csc[s]);
        v[5] = (_Float16)(a1.y * csc[s]);
        v[6] = (_Float16)(a1.z * csc[s]);
        v[7] = (_Float16)(a1.w * csc[s]);
        af[s] = v;
      }
#pragma unroll
      for (int nt = 0; nt < 8; nt++) {
        f16x8 wf = *(const f16x8*)&Wt[nt * 16 + li][kc + q * 8];
        acc[0][nt] = __builtin_amdgcn_mfma_f32_16x16x32_f16(wf, af[0], acc[0][nt], 0, 0, 0);
        acc[1][nt] = __builtin_amdgcn_mfma_f32_16x16x32_f16(wf, af[1], acc[1][nt], 0, 0, 0);
      }
    }

#pragma unroll
    for (int s = 0; s < 2; s++) {
      if (!mok[s]) continue;
      size_t rb = (size_t)mrow[s] * 128;
#pragma unroll
      for (int nt = 0; nt < 8; nt++) {
        __half2 p0 = __floats2half2_rn(acc[s][nt][0], acc[s][nt][1]);
        __half2 p1 = __floats2half2_rn(acc[s][nt][2], acc[s][nt][3]);
        uint2 qv;
        qv.x = *(unsigned*)&p0;
        qv.y = *(unsigned*)&p1;
        *(uint2*)&out[rb + nt * 16 + q * 4] = qv;
      }
    }
  }
}

// ---------------- MFMA GEMM (R13 LDS form): out[m][n] = (sum_k A[m][k]*sc[m]*W[k][n]) -> fp16 ----------------

__device__ __forceinline__ f16x8 load_af(const __half* arow, int off, float csc) {
  f16x8 v = *(const f16x8*)(arow + off);
  _Float16 c = (_Float16)csc;
#pragma unroll
  for (int j = 0; j < 8; j++) v[j] = v[j] * c;
  return v;
}

__global__ __launch_bounds__(256) void k_gemm_mfma_h(const __half* __restrict__ A, const float* __restrict__ W,
                                                     const float* __restrict__ scale, __half* __restrict__ out, int N) {
  __shared__ _Float16 Wt[128][136];
  int t = threadIdx.x;
  {
    int nlow = t & 15;
    int kplow = t >> 4;
#pragma unroll
    for (int j = 0; j < 32; j++) {
      int n = nlow + 16 * (j & 7);
      int kp = kplow + 16 * (j >> 3);
      float w0 = W[(size_t)(2 * kp) * 128 + n];
      float w1 = W[(size_t)(2 * kp + 1) * 128 + n];
      __half2 h2 = __floats2half2_rn(w0, w1);
      *(__half2*)&Wt[n][2 * kp] = h2;
    }
  }
  __syncthreads();

  int wave = t >> 6;
  int lane = t & 63;
  int li = lane & 15;
  int q = lane >> 4;

#pragma unroll
  for (int s2 = 0; s2 < 2; s2++) {
    int m0 = (blockIdx.x * 2 + s2) * 128 + wave * 32;
    if (m0 >= N) break;

    int mrow[2];
    float csc[2];
    bool mok[2];
    const __half* arow[2];
#pragma unroll
    for (int s = 0; s < 2; s++) {
      mrow[s] = m0 + s * 16 + li;
      mok[s] = mrow[s] < N;
      csc[s] = mok[s] ? scale[mrow[s]] : 0.f;
      arow[s] = A + (size_t)(mok[s] ? mrow[s] : 0) * 128;
    }

    f32x4 acc[2][8];
#pragma unroll
    for (int s = 0; s < 2; s++)
#pragma unroll
      for (int nt = 0; nt < 8; nt++) acc[s][nt] = (f32x4){0.f, 0.f, 0.f, 0.f};

#pragma unroll
    for (int kc = 0; kc < 128; kc += 32) {
      f16x8 af[2];
#pragma unroll
      for (int s = 0; s < 2; s++) af[s] = load_af(arow[s], kc + q * 8, csc[s]);
#pragma unroll
      for (int nt = 0; nt < 8; nt++) {
        f16x8 wf = *(const f16x8*)&Wt[nt * 16 + li][kc + q * 8];
        acc[0][nt] = __builtin_amdgcn_mfma_f32_16x16x32_f16(wf, af[0], acc[0][nt], 0, 0, 0);
        acc[1][nt] = __builtin_amdgcn_mfma_f32_16x16x32_f16(wf, af[1], acc[1][nt], 0, 0, 0);
      }
    }

#pragma unroll
    for (int s = 0; s < 2; s++) {
      if (!mok[s]) continue;
      size_t rb = (size_t)mrow[s] * 128;
#pragma unroll
      for (int nt = 0; nt < 8; nt++) {
        __half2 p0 = __floats2half2_rn(acc[s][nt][0], acc[s][nt][1]);
        __half2 p1 = __floats2half2_rn(acc[s][nt][2], acc[s][nt][3]);
        uint2 qv;
        qv.x = *(unsigned*)&p0;
        qv.y = *(unsigned*)&p1;
        *(uint2*)&out[rb + nt * 16 + q * 4] = qv;
      }
    }
  }
}

// ---------------- Sparse aggregation: fp16 rows in, fp16 out (R9 shape: one 256-B row per wave,
//                  two 32-lane halves split the edge list; no LDS/barriers) ----------------

__device__ __forceinline__ void acc_pair(float4& a, uint2 qa, uint2 qb) {
  __half2 s0 = __hadd2(*(__half2*)&qa.x, *(__half2*)&qb.x);
  __half2 s1 = __hadd2(*(__half2*)&qa.y, *(__half2*)&qb.y);
  float2 f0 = __half22float2(s0);
  float2 f1 = __half22float2(s1);
  a.x += f0.x; a.y += f0.y; a.z += f1.x; a.w += f1.y;
}

__device__ __forceinline__ void acc_one(float4& a, uint2 q) {
  float2 f0 = __half22float2(*(__half2*)&q.x);
  float2 f1 = __half22float2(*(__half2*)&q.y);
  a.x += f0.x; a.y += f0.y; a.z += f1.x; a.w += f1.y;
}

__global__ __launch_bounds__(256) void k_aggregate_h(const __half* __restrict__ hin, const int* __restrict__ rp,
                                                     const int* __restrict__ ci, const float* __restrict__ c_dst,
                                                     const float* __restrict__ bias, __half* __restrict__ hout, int N) {
  int v = blockIdx.x * 4 + (threadIdx.x >> 6);
  if (v >= N) return;
  int half_id = (threadIdx.x >> 5) & 1;
  int f4 = (threadIdx.x & 31) * 4;
  const char* hb = (const char*)hin + f4 * 2;
  int p0 = rp[v], pe = rp[v + 1];
  int mid = p0 + ((pe - p0 + 1) >> 1);
  int p = half_id ? mid : p0;
  int pend = half_id ? pe : mid;
  float4 a0 = make_float4(0.f, 0.f, 0.f, 0.f);
  float4 a1 = make_float4(0.f, 0.f, 0.f, 0.f);
  float4 a2 = make_float4(0.f, 0.f, 0.f, 0.f);
  float4 a3 = make_float4(0.f, 0.f, 0.f, 0.f);
  for (; p + 7 < pend; p += 8) {
    int u0 = ci[p];
    int u1 = ci[p + 1];
    int u2 = ci[p + 2];
    int u3 = ci[p + 3];
    int u4 = ci[p + 4];
    int u5 = ci[p + 5];
    int u6 = ci[p + 6];
    int u7 = ci[p + 7];
    uint2 q0 = *(const uint2*)(hb + (size_t)(unsigned)u0);
    uint2 q1 = *(const uint2*)(hb + (size_t)(unsigned)u1);
    uint2 q2 = *(const uint2*)(hb + (size_t)(unsigned)u2);
    uint2 q3 = *(const uint2*)(hb + (size_t)(unsigned)u3);
    uint2 q4 = *(const uint2*)(hb + (size_t)(unsigned)u4);
    uint2 q5 = *(const uint2*)(hb + (size_t)(unsigned)u5);
    uint2 q6 = *(const uint2*)(hb + (size_t)(unsigned)u6);
    uint2 q7 = *(const uint2*)(hb + (size_t)(unsigned)u7);
    acc_pair(a0, q0, q1);
    acc_pair(a1, q2, q3);
    acc_pair(a2, q4, q5);
    acc_pair(a3, q6, q7);
  }
  for (; p + 1 < pend; p += 2) {
    int u0 = ci[p];
    int u1 = ci[p + 1];
    uint2 q0 = *(const uint2*)(hb + (size_t)(unsigned)u0);
    uint2 q1 = *(const uint2*)(hb + (size_t)(unsigned)u1);
    acc_pair(a0, q0, q1);
  }
  if (p < pend) {
    uint2 q = *(const uint2*)(hb + (size_t)(unsigned)ci[p]);
    acc_one(a0, q);
  }
  a0.x += a1.x; a0.y += a1.y; a0.z += a1.z; a0.w += a1.w;
  a2.x += a3.x; a2.y += a3.y; a2.z += a3.z; a2.w += a3.w;
  a0.x += a2.x; a0.y += a2.y; a0.z += a2.z; a0.w += a2.w;
  a0.x += __shfl_xor(a0.x, 32);
  a0.y += __shfl_xor(a0.y, 32);
  a0.z += __shfl_xor(a0.z, 32);
  a0.w += __shfl_xor(a0.w, 32);
  if (half_id == 0) {
    float cd = c_dst[v];
    float4 b = *(const float4*)&bias[f4];
    float4 o;
    o.x = fmaxf(fmaf(a0.x, cd, b.x), 0.f);
    o.y = fmaxf(fmaf(a0.y, cd, b.y), 0.f);
    o.z = fmaxf(fmaf(a0.z, cd, b.z), 0.f);
    o.w = fmaxf(fmaf(a0.w, cd, b.w), 0.f);
    __half2 p0h = __floats2half2_rn(o.x, o.y);
    __half2 p1h = __floats2half2_rn(o.z, o.w);
    uint2 qv;
    qv.x = *(unsigned*)&p0h;
    qv.y = *(unsigned*)&p1h;
    *(uint2*)&hout[(size_t)v * 128 + f4] = qv;
  }
}

// ---------------- Classifier (MFMA, R13 LDS form): out[N,47] = h @ Wc + bc, Wc hi+lo fp16 ----------------

__global__ __launch_bounds__(256) void k_classifier_mfma(const __half* __restrict__ h, const float* __restrict__ Wc,
                                                         const float* __restrict__ bc, float* __restrict__ out, int N) {
  __shared__ _Float16 Wt[96][136];   // rows 0..47: hi(Wc^T); rows 48..95: fp16 residual
  __shared__ float bs[48];
  int t = threadIdx.x;
  if (t < 47) bs[t] = bc[t];
  if (t == 47) bs[47] = 0.f;
  for (int i = t; i < 48 * 128; i += 256) {
    int n = i >> 7, k = i & 127;
    float w = (n < 47) ? Wc[(size_t)k * 47 + n] : 0.f;
    _Float16 hi = (_Float16)w;
    Wt[n][k] = hi;
    Wt[n + 48][k] = (_Float16)(w - (float)hi);
  }
  __syncthreads();

  int wave = t >> 6;
  int lane = t & 63;
  int li = lane & 15;
  int q = lane >> 4;

#pragma unroll
  for (int s2 = 0; s2 < 2; s2++) {
    int m0 = (blockIdx.x * 2 + s2) * 128 + wave * 32;
    if (m0 >= N) break;

    int mrow[2];
    bool mok[2];
    const __half* arow[2];
#pragma unroll
    for (int s = 0; s < 2; s++) {
      mrow[s] = m0 + s * 16 + li;
      mok[s] = mrow[s] < N;
      arow[s] = h + (size_t)(mok[s] ? mrow[s] : 0) * 128;
    }

    f32x4 acc[2][3];
#pragma unroll
    for (int s = 0; s < 2; s++)
#pragma unroll
      for (int nt = 0; nt < 3; nt++) acc[s][nt] = (f32x4){0.f, 0.f, 0.f, 0.f};

#pragma unroll
    for (int kc = 0; kc < 128; kc += 32) {
      f16x8 af[2];
#pragma unroll
      for (int s = 0; s < 2; s++) af[s] = *(const f16x8*)(arow[s] + kc + q * 8);
#pragma unroll
      for (int nt = 0; nt < 3; nt++) {
        f16x8 whi = *(const f16x8*)&Wt[nt * 16 + li][kc + q * 8];
        f16x8 wlo = *(const f16x8*)&Wt[48 + nt * 16 + li][kc + q * 8];
        acc[0][nt] = __builtin_amdgcn_mfma_f32_16x16x32_f16(whi, af[0], acc[0][nt], 0, 0, 0);
        acc[1][nt] = __builtin_amdgcn_mfma_f32_16x16x32_f16(whi, af[1], acc[1][nt], 0, 0, 0);
        acc[0][nt] = __builtin_amdgcn_mfma_f32_16x16x32_f16(wlo, af[0], acc[0][nt], 0, 0, 0);
        acc[1][nt] = __builtin_amdgcn_mfma_f32_16x16x32_f16(wlo, af[1], acc[1][nt], 0, 0, 0);
      }
    }

#pragma unroll
    for (int s = 0; s < 2; s++) {
      if (!mok[s]) continue;
      size_t rb = (size_t)mrow[s] * 47;
#pragma unroll
      for (int nt = 0; nt < 3; nt++) {
#pragma unroll
        for (int j = 0; j < 4; j++) {
          int c = nt * 16 + q * 4 + j;
          if (c < 47) out[rb + c] = acc[s][nt][j] + bs[c];
        }
      }
    }
  }
}

// ---------------- launch ----------------

extern "C" void kernel_launch(void* const* d_in, const int* in_sizes, int n_in,
                              void* d_out, int out_size, void* d_ws, size_t ws_size,
                              hipStream_t stream) {
  const float* x  = (const float*)d_in[0];
  const int* edges = (const int*)d_in[1];
  const float* W0 = (const float*)d_in[2];
  const float* b0 = (const float*)d_in[3];
  const float* W1 = (const float*)d_in[4];
  const float* b1 = (const float*)d_in[5];
  const float* Wc = (const float*)d_in[6];
  const float* bc = (const float*)d_in[7];
  float* out = (float*)d_out;

  int N = in_sizes[0] / 128;
  int E = in_sizes[1] / 2;
  const int* src = edges;
  const int* dst = edges + E;

  int NB = (N + ((1 << BSHIFT) - 1)) >> BSHIFT;   // 391 (<=512 required)
  int src_bits = 0;
  while ((1 << src_bits) < N) src_bits++;          // 17
  int per_blk = (E + PB - 1) / PB;

  char* base = (char*)d_ws;
  size_t off = 0;
  auto alloc = [&](size_t bytes) -> void* {
    void* p = base + off;
    off += (bytes + 255) & ~(size_t)255;
    return p;
  };
  float* c_src = (float*)alloc((size_t)N * 4);
  float* c_dst = (float*)alloc((size_t)N * 4);
  int* row_ptr = (int*)alloc((size_t)(N + 1) * 4);
  int* col_idx = (int*)alloc((size_t)E * 4);
  __half* h0h = (__half*)alloc((size_t)N * 128 * 2);   // GEMM outputs (fp16, 25.6 MB)
  __half* h1h = (__half*)alloc((size_t)N * 128 * 2);   // aggregate outputs (fp16, 25.6 MB)

  // build-time scratch carved out of h1h (dead until first k_aggregate writes it)
  char* hb = (char*)h1h;
  unsigned* ebuf = (unsigned*)hb;            hb += (size_t)E * 4;
  unsigned char* sbuf = (unsigned char*)hb;  hb += ((size_t)E + 255) & ~(size_t)255;
  int* cntT = (int*)hb;                      hb += (size_t)2 * NB * PB * 4;   // [dst | src]
  int* offsT = (int*)hb;                     hb += (size_t)2 * NB * PB * 4;
  int* total = (int*)hb;                     hb += (size_t)2 * NB * 4;
  int* bbase = (int*)hb;                     hb += (size_t)(NB + 1) * 4;
  int* sbase = (int*)hb;                     hb += (size_t)(NB + 1) * 4;
  int* cntT2 = cntT + (size_t)NB * PB;
  int* offsT2 = offsT + (size_t)NB * PB;

  k_count<<<PB, 256, 0, stream>>>(src, dst, E, per_blk, NB, cntT, cntT2);
  k_scanblk<<<2 * NB, 256, 0, stream>>>(cntT, offsT, total);
  k_scantot<<<2, 512, 0, stream>>>(total, NB, E, bbase, sbase, row_ptr, N);
  k_partition<<<PB, 256, 0, stream>>>(src, dst, E, per_blk, NB, offsT, bbase, offsT2, sbase,
                                      ebuf, sbuf, src_bits);
  k_finalize_src<<<NB, 256, 0, stream>>>(sbuf, sbase, N, c_src);

  int strips = (N + 127) / 128;
  int gblocks = (strips + 1) / 2;   // 391
  // fused: finalize_dst (blocks 0..NB-1) overlapped with gemm1 (blocks NB..NB+gblocks-1)
  k_fin_gemm<<<NB + gblocks, 256, 0, stream>>>(ebuf, bbase, N, src_bits, NB,
                                               row_ptr, c_dst, col_idx,
                                               x, W0, c_src, h0h);
  k_aggregate_h<<<(N + 3) / 4, 256, 0, stream>>>(h0h, row_ptr, col_idx, c_dst, b0, h1h, N);
  k_gemm_mfma_h<<<gblocks, 256, 0, stream>>>(h1h, W1, c_src, h0h, N);
  k_aggregate_h<<<(N + 3) / 4, 256, 0, stream>>>(h0h, row_ptr, col_idx, c_dst, b1, h1h, N);
  k_classifier_mfma<<<gblocks, 256, 0, stream>>>(h1h, Wc, bc, out, N);
}